// Round 2
// baseline (2292.980 us; speedup 1.0000x reference)
//
#include <hip/hip_runtime.h>
#include <math.h>

#define BATCH 2
#define SEQ 4096
#define DM 1024
#define NH 16
#define DK 64
#define DV 128
#define NC 64     // number of chunks
#define CL 64     // chunk length
#define ROWS (BATCH*SEQ)   // 8192
#define DG (DM*2)          // 2048 (val/gate width)

__device__ __forceinline__ float head_decay(int h) {
    return logf(1.0f - exp2f(-5.0f - (float)h));
}

// ---------------- LN stats: mu/rstd per row (LN applied inside GEMM A-load) ----------------
__global__ __launch_bounds__(256) void ln_stats_kernel(const float* __restrict__ x,
                                                       float* __restrict__ stats) {
    int row = blockIdx.x;
    const float* xr = x + (size_t)row * DM;
    float s1 = 0.f, s2 = 0.f;
#pragma unroll
    for (int t = 0; t < 4; t++) {
        float v = xr[threadIdx.x + t*256];
        s1 += v; s2 += v*v;
    }
#pragma unroll
    for (int off = 32; off > 0; off >>= 1) {
        s1 += __shfl_down(s1, off);
        s2 += __shfl_down(s2, off);
    }
    __shared__ float a1[4], a2[4];
    int wid = threadIdx.x >> 6;
    if ((threadIdx.x & 63) == 0) { a1[wid] = s1; a2[wid] = s2; }
    __syncthreads();
    if (threadIdx.x == 0) {
        s1 = a1[0]+a1[1]+a1[2]+a1[3];
        s2 = a2[0]+a2[1]+a2[2]+a2[3];
        float mu = s1 * (1.f/DM);
        float var = s2 * (1.f/DM) - mu*mu;
        stats[2*row]   = mu;
        stats[2*row+1] = rsqrtf(var + 1e-5f);
    }
}

// ---------------- NT GEMM: C = (LN?(A) @ W^T + bias) * scale, optional fused RoPE ----------------
#define BM 64
#define BN 64
#define BK 16
template<bool FUSE_LN, bool ROPE>
__global__ __launch_bounds__(256) void gemm_nt(
        const float* __restrict__ A, const float* __restrict__ W,
        const float* __restrict__ bias, float* __restrict__ C,
        int M, int N, int K, float scale,
        const float* __restrict__ stats, const float* __restrict__ lng,
        const float* __restrict__ lnb) {
    __shared__ float As[BK][BM+4];   // +4 pad keeps float4 alignment, conflict-free
    __shared__ float Bs[BK][BN+4];
    const int bm = blockIdx.y * BM;
    const int bn = blockIdx.x * BN;
    const int tid = threadIdx.x;
    const int tx = tid & 15, ty = tid >> 4;
    float acc[4][4] = {};
    const float* Ap = A + (size_t)bm * K;
    const float* Wp = W + (size_t)bn * K;
    float mu_[4], rs_[4];
    if (FUSE_LN) {
#pragma unroll
        for (int t = 0; t < 4; t++) {
            int r = bm + ty + t*16;
            mu_[t] = stats[2*r];
            rs_[t] = stats[2*r+1];
        }
    }
    for (int k0 = 0; k0 < K; k0 += BK) {
        float gk = 0.f, bk = 0.f;
        if (FUSE_LN) { gk = lng[k0 + tx]; bk = lnb[k0 + tx]; }
#pragma unroll
        for (int t = 0; t < 4; t++) {
            int r = ty + t*16;
            float a = Ap[(size_t)r*K + k0 + tx];
            if (FUSE_LN) a = (a - mu_[t]) * rs_[t] * gk + bk;
            As[tx][r] = a;
            Bs[tx][r] = Wp[(size_t)r*K + k0 + tx];
        }
        __syncthreads();
#pragma unroll
        for (int kk = 0; kk < BK; kk++) {
            float4 av = *(const float4*)&As[kk][ty*4];
            float4 bv = *(const float4*)&Bs[kk][tx*4];
            float aa[4] = {av.x, av.y, av.z, av.w};
            float bb[4] = {bv.x, bv.y, bv.z, bv.w};
#pragma unroll
            for (int i = 0; i < 4; i++)
#pragma unroll
                for (int j = 0; j < 4; j++)
                    acc[i][j] += aa[i]*bb[j];
        }
        __syncthreads();
    }
#pragma unroll
    for (int i = 0; i < 4; i++) {
        int r = bm + ty*4 + i;
        if (ROPE) {
            int s = r & (SEQ-1);
#pragma unroll
            for (int j = 0; j < 4; j += 2) {
                int cc = bn + tx*4 + j;        // even
                float t0 = (acc[i][j]   + bias[cc])   * scale;
                float t1 = (acc[i][j+1] + bias[cc+1]) * scale;
                int jj = (cc & 63) >> 1;       // within-head pair index 0..31
                // 10000^(-jj/31) = 2^(-jj*log2(10000)/31)
                float ang = exp2f(-(float)jj * (13.287712379549449f/31.f));
                float th = (float)s * ang;
                float sn, cs;
                sincosf(th, &sn, &cs);
                C[(size_t)r*N + cc]   = t0*cs - t1*sn;
                C[(size_t)r*N + cc+1] = t1*cs + t0*sn;
            }
        } else {
#pragma unroll
            for (int j = 0; j < 4; j++) {
                int cc = bn + tx*4 + j;
                C[(size_t)r*N + cc] = (acc[i][j] + bias[cc]) * scale;
            }
        }
    }
}

// ---------------- retention per-chunk: inner_out (in-place over val), KV, inner_scale ----------------
__global__ __launch_bounds__(256) void ret_inner_kernel(
        const float* __restrict__ qry, const float* __restrict__ key,
        float* __restrict__ valio, float* __restrict__ kv_out,
        float* __restrict__ iscale_out) {
    int blk = blockIdx.x;           // (b*NH + h)*NC + c
    int c = blk & 63;
    int h = (blk >> 6) & 15;
    int b = blk >> 10;
    float dec = head_decay(h);

    __shared__ float uni[64*65];    // Q (stride 65) in phase 1, V half (stride 64) in phase 2
    __shared__ float Ks[CL][DK+1];
    __shared__ float Ss[CL][CL+1];
    __shared__ float ascale[CL];
    __shared__ float iscale[CL];

    int tid = threadIdx.x;
    size_t qkbase = ((size_t)(b*SEQ + c*CL))*DM + (size_t)h*DK;
#pragma unroll
    for (int t = 0; t < 16; t++) {
        int idx = tid + t*256;
        int i = idx >> 6, d = idx & 63;
        uni[i*65 + d] = qry[qkbase + (size_t)i*DM + d];
        Ks[i][d]      = key[qkbase + (size_t)i*DM + d];
    }
    if (tid < CL) {                 // attn_scale by explicit series (closed form cancels at h=15)
        float ssum = 0.f;
        for (int t = 0; t <= tid; t++) ssum += expf(dec * (float)t);
        ascale[tid] = sqrtf(ssum);
    }
    __syncthreads();

    // S = (Q @ K^T) * mask / ascale
    {
        int tx = tid & 15, ty = tid >> 4;
        float acc[4][4] = {};
        for (int d = 0; d < DK; d++) {
            float av[4], bv[4];
#pragma unroll
            for (int i = 0; i < 4; i++) av[i] = uni[(ty*4+i)*65 + d];
#pragma unroll
            for (int j = 0; j < 4; j++) bv[j] = Ks[tx*4+j][d];
#pragma unroll
            for (int i = 0; i < 4; i++)
#pragma unroll
                for (int j = 0; j < 4; j++)
                    acc[i][j] += av[i]*bv[j];
        }
#pragma unroll
        for (int i = 0; i < 4; i++) {
            int ri = ty*4 + i;
            float ra = 1.f / ascale[ri];
#pragma unroll
            for (int j = 0; j < 4; j++) {
                int cj = tx*4 + j;
                float m = (cj <= ri) ? expf(dec*(float)(ri-cj)) * ra : 0.f;
                Ss[ri][cj] = acc[i][j] * m;
            }
        }
    }
    __syncthreads();
    if (tid < CL) {                 // inner_scale = max(|row sum|, 1)
        float rs = 0.f;
        for (int j = 0; j < CL; j++) rs += Ss[tid][j];
        float isc = fmaxf(fabsf(rs), 1.f);
        iscale[tid] = isc;
        iscale_out[(size_t)blk*CL + tid] = isc;
    }

    // phase 2: (S/iscale)@V and K^T@V, V in two 64-col halves overlaying dead Q
    int txv = tid & 15, tyv = tid >> 4;
    int v0 = txv*4, i0 = tyv*4;
    size_t vbase = ((size_t)(b*SEQ + c*CL))*DG + (size_t)h*DV;
    for (int half = 0; half < 2; half++) {
        __syncthreads();            // prior uni readers done; iscale visible
#pragma unroll
        for (int t = 0; t < 16; t++) {
            int idx = tid + t*256;
            int i = idx >> 6, d = idx & 63;
            uni[i*64 + d] = valio[vbase + (size_t)i*DG + half*64 + d];
        }
        __syncthreads();
        float acc2[4][4] = {};
        float acc3[4][4] = {};
        for (int j = 0; j < CL; j++) {
            float4 vv = *(const float4*)&uni[j*64 + v0];
            float va[4] = {vv.x, vv.y, vv.z, vv.w};
#pragma unroll
            for (int r = 0; r < 4; r++) {
                float s  = Ss[i0+r][j];
                float kk = Ks[j][i0+r];
#pragma unroll
                for (int q = 0; q < 4; q++) {
                    acc2[r][q] += s*va[q];
                    acc3[r][q] += kk*va[q];
                }
            }
        }
#pragma unroll
        for (int r = 0; r < 4; r++) {
            int i = i0 + r;
            float inv = 1.f / iscale[i];
            float4 o = make_float4(acc2[r][0]*inv, acc2[r][1]*inv,
                                   acc2[r][2]*inv, acc2[r][3]*inv);
            *(float4*)&valio[vbase + (size_t)i*DG + half*64 + v0] = o;   // own elements only
            float4 kvo = make_float4(acc3[r][0], acc3[r][1], acc3[r][2], acc3[r][3]);
            *(float4*)&kv_out[(size_t)blk*(DK*DV) + (size_t)i*DV + half*64 + v0] = kvo;
        }
    }
}

// ---------------- sequential scan over chunks (in-place KV -> cross_chunk) ----------------
__global__ __launch_bounds__(256) void ret_scan_kernel(float* __restrict__ kv,
        float* __restrict__ cscale_out) {
    int tid = threadIdx.x;
    int col = blockIdx.x*16 + ((tid >> 6) << 2) + (tid & 3);  // 0..4095
    int kp  = (tid >> 2) & 15;
    int v   = col & 127;
    int bh  = col >> 7;
    int h   = bh & 15;
    float dec = head_decay(h);
    float cdecay = expf(dec * (float)CL);
    float state[4] = {0.f, 0.f, 0.f, 0.f};
    float scale = 1.f;
    size_t base0 = (size_t)bh*NC*(DK*DV) + (size_t)(kp*4)*DV + v;
    float cur[4];
#pragma unroll
    for (int kk = 0; kk < 4; kk++) cur[kk] = kv[base0 + (size_t)kk*DV];
    for (int c = 0; c < NC; c++) {
        size_t base = base0 + (size_t)c*(DK*DV);
        float nxt[4];
        if (c+1 < NC) {             // software-pipelined next-chunk load
            size_t nb = base + (size_t)(DK*DV);
#pragma unroll
            for (int kk = 0; kk < 4; kk++) nxt[kk] = kv[nb + (size_t)kk*DV];
        }
        float inv = 1.f / scale;
#pragma unroll
        for (int kk = 0; kk < 4; kk++) kv[base + (size_t)kk*DV] = cur[kk]*inv;
        if (kp == 0) cscale_out[((size_t)bh*NC + c)*DV + v] = scale;
        float ssum = 0.f;
#pragma unroll
        for (int kk = 0; kk < 4; kk++) {
            state[kk] = state[kk]*cdecay + cur[kk];
            ssum += fabsf(state[kk]);
        }
        ssum += __shfl_xor(ssum, 4);
        ssum += __shfl_xor(ssum, 8);
        ssum += __shfl_xor(ssum, 16);
        ssum += __shfl_xor(ssum, 32);
        scale = fmaxf(ssum, 1.f);
        if (c+1 < NC) {
#pragma unroll
            for (int kk = 0; kk < 4; kk++) cur[kk] = nxt[kk];
        }
    }
}

// ---------------- cross_out + combine + groupnorm + silu(gate), in place over valio ----------------
__global__ __launch_bounds__(256) void ret_cross_kernel(
        const float* __restrict__ qry, const float* __restrict__ cross_chunk,
        float* __restrict__ valio, const float* __restrict__ iscale,
        const float* __restrict__ cscale, const float* __restrict__ gate,
        const float* __restrict__ gn_g, const float* __restrict__ gn_b) {
    int blk = blockIdx.x;
    int c = blk & 63, h = (blk >> 6) & 15, b = blk >> 10;
    float dec = head_decay(h);
    __shared__ float Qs[CL][DK+1];
    __shared__ float CC[DK][DV];
    __shared__ float asc[CL];
    __shared__ float idec[CL];

    int tid = threadIdx.x;
    size_t qbase = ((size_t)(b*SEQ + c*CL))*DM + (size_t)h*DK;
#pragma unroll
    for (int t = 0; t < 16; t++) {
        int idx = tid + t*256;
        int i = idx >> 6, d = idx & 63;
        Qs[i][d] = qry[qbase + (size_t)i*DM + d];
    }
    size_t cbase = (size_t)blk * (DK*DV);
#pragma unroll
    for (int t = 0; t < 32; t++) {
        int idx = tid + t*256;
        CC[idx >> 7][idx & 127] = cross_chunk[cbase + idx];
    }
    if (tid < CL) {
        float ssum = 0.f;
        for (int t = 0; t <= tid; t++) ssum += expf(dec * (float)t);
        asc[tid] = sqrtf(ssum);
    }
    __syncthreads();
    if (tid < CL) idec[tid] = expf(dec*(float)(tid+1)) * asc[CL-1] / asc[tid];
    __syncthreads();

    int txv = tid & 31, tyv = tid >> 5;
    int v0 = txv*4, i0 = tyv*8;
    float acc[8][4] = {};
    for (int k = 0; k < DK; k++) {
        float4 cv = *(const float4*)&CC[k][v0];
        float ca[4] = {cv.x, cv.y, cv.z, cv.w};
#pragma unroll
        for (int r = 0; r < 8; r++) {
            float qv = Qs[i0+r][k];
#pragma unroll
            for (int q = 0; q < 4; q++) acc[r][q] += qv*ca[q];
        }
    }
    float4 csv = *(const float4*)&cscale[(size_t)blk*DV + v0];
    float csa[4] = {csv.x, csv.y, csv.z, csv.w};
    float o[8][4];
    float s1[8], s2[8];
#pragma unroll
    for (int r = 0; r < 8; r++) {
        int i = i0 + r;
        float f2 = idec[i] / iscale[(size_t)blk*CL + i];
        size_t orow = ((size_t)(b*SEQ + c*CL + i))*DG + (size_t)h*DV + v0;
        float4 io = *(const float4*)&valio[orow];
        float ioa[4] = {io.x, io.y, io.z, io.w};
        float rs1 = 0.f, rs2 = 0.f;
#pragma unroll
        for (int q = 0; q < 4; q++) {
            float ov = ioa[q]/csa[q] + acc[r][q]*f2;
            o[r][q] = ov;
            rs1 += ov; rs2 += ov*ov;
        }
        s1[r] = rs1; s2[r] = rs2;
    }
    // groupnorm over the head's 128 v's: reduce across 32 txv lanes (masks stay in-half-wave)
#pragma unroll
    for (int r = 0; r < 8; r++) {
#pragma unroll
        for (int m = 1; m <= 16; m <<= 1) {
            s1[r] += __shfl_xor(s1[r], m);
            s2[r] += __shfl_xor(s2[r], m);
        }
    }
#pragma unroll
    for (int r = 0; r < 8; r++) {
        int i = i0 + r;
        float mu = s1[r] * (1.f/DV);
        float var = s2[r] * (1.f/DV) - mu*mu;
        float rstd = rsqrtf(var + 1e-5f);
        size_t orow = ((size_t)(b*SEQ + c*CL + i))*DG + (size_t)h*DV + v0;
        float4 gv = *(const float4*)&gate[orow];
        float ga[4] = {gv.x, gv.y, gv.z, gv.w};
        float4 res;
        float* rp = (float*)&res;
#pragma unroll
        for (int q = 0; q < 4; q++) {
            int col = h*DV + v0 + q;
            float xn = (o[r][q] - mu)*rstd*gn_g[col] + gn_b[col];
            float sg = ga[q] / (1.f + expf(-ga[q]));
            rp[q] = xn * sg;
        }
        *(float4*)&valio[orow] = res;
    }
}

extern "C" void kernel_launch(void* const* d_in, const int* in_sizes, int n_in,
                              void* d_out, int out_size, void* d_ws, size_t ws_size,
                              hipStream_t stream) {
    (void)in_sizes; (void)n_in; (void)out_size; (void)ws_size;
    const float* x    = (const float*)d_in[0];
    const float* W_q  = (const float*)d_in[2];
    const float* b_q  = (const float*)d_in[3];
    const float* W_k  = (const float*)d_in[4];
    const float* b_k  = (const float*)d_in[5];
    const float* W_v  = (const float*)d_in[6];
    const float* b_v  = (const float*)d_in[7];
    const float* W_g  = (const float*)d_in[8];
    const float* b_g  = (const float*)d_in[9];
    const float* W_o  = (const float*)d_in[10];
    const float* b_o  = (const float*)d_in[11];
    const float* ln_g = (const float*)d_in[12];
    const float* ln_b = (const float*)d_in[13];
    const float* gn_g = (const float*)d_in[14];
    const float* gn_b = (const float*)d_in[15];
    float* out = (float*)d_out;
    float* ws  = (float*)d_ws;

    // workspace layout (floats) — total 59,129,856 floats = 225.6 MB
    float* key    = ws;                       //  8,388,608 (32 MB)
    float* valio  = key    + 8388608;         // 16,777,216 (64 MB): val -> inner_out -> pre-Wo acts
    float* gate   = valio  + 16777216;        // 16,777,216 (64 MB)
    float* kvbuf  = gate   + 16777216;        // 16,777,216 (64 MB): KV -> cross_chunk in place
    float* stats  = kvbuf  + 16777216;        //     16,384 (mu,rstd interleaved)
    float* iscale = stats  + 16384;           //    131,072
    float* cscale = iscale + 131072;          //    262,144
    float* qry    = out;                      // d_out doubles as qry scratch (dead before final GEMM)

    ln_stats_kernel<<<ROWS, 256, 0, stream>>>(x, stats);

    dim3 gq(DM/BN, ROWS/BM);
    dim3 gv(DG/BN, ROWS/BM);
    gemm_nt<true,true ><<<gq, 256, 0, stream>>>(x, W_q, b_q, qry,   ROWS, DM, DM, 1.f,    stats, ln_g, ln_b);
    gemm_nt<true,true ><<<gq, 256, 0, stream>>>(x, W_k, b_k, key,   ROWS, DM, DM, 0.125f, stats, ln_g, ln_b);
    gemm_nt<true,false><<<gv, 256, 0, stream>>>(x, W_v, b_v, valio, ROWS, DG, DM, 1.f,    stats, ln_g, ln_b);
    gemm_nt<true,false><<<gv, 256, 0, stream>>>(x, W_g, b_g, gate,  ROWS, DG, DM, 1.f,    stats, ln_g, ln_b);

    ret_inner_kernel<<<BATCH*NH*NC, 256, 0, stream>>>(qry, key, valio, kvbuf, iscale);
    ret_scan_kernel<<<256, 256, 0, stream>>>(kvbuf, cscale);
    ret_cross_kernel<<<BATCH*NH*NC, 256, 0, stream>>>(qry, kvbuf, valio, iscale, cscale,
                                                      gate, gn_g, gn_b);

    gemm_nt<false,false><<<gq, 256, 0, stream>>>(valio, W_o, b_o, out, ROWS, DM, DG, 1.f,
                                                 nullptr, nullptr, nullptr);
}

// Round 3
// 1218.028 us; speedup vs baseline: 1.8825x; 1.8825x over previous
//
#include <hip/hip_runtime.h>
#include <hip/hip_bf16.h>
#include <math.h>

#define BATCH 2
#define SEQ 4096
#define DM 1024
#define NH 16
#define DK 64
#define DV 128
#define NC 64     // number of chunks
#define CL 64     // chunk length
#define ROWS (BATCH*SEQ)   // 8192
#define DG (DM*2)          // 2048 (val/gate width)

typedef __attribute__((ext_vector_type(8))) short short8;
typedef __attribute__((ext_vector_type(4))) float floatx4;

__device__ __forceinline__ float head_decay(int h) {
    return logf(1.0f - exp2f(-5.0f - (float)h));
}
__device__ __forceinline__ unsigned short bfbits(float v) {
    __hip_bfloat16 h = __float2bfloat16(v);
    return *(unsigned short*)&h;
}
__device__ __forceinline__ float bf2f(unsigned short u) {
    unsigned x = ((unsigned)u) << 16;
    return *(float*)&x;
}
__device__ __forceinline__ unsigned pack2(float a, float b) {
    return (unsigned)bfbits(a) | ((unsigned)bfbits(b) << 16);
}
__device__ __forceinline__ void gld_lds16(const unsigned short* g, unsigned short* l) {
    __builtin_amdgcn_global_load_lds(
        (const __attribute__((address_space(1))) unsigned int*)g,
        (__attribute__((address_space(3))) unsigned int*)l, 16, 0, 0);
}

// ---------------- LN + cast to bf16: one block per row ----------------
__global__ __launch_bounds__(256) void ln_cvt_kernel(const float* __restrict__ x,
        const float* __restrict__ g, const float* __restrict__ b,
        unsigned short* __restrict__ xbf) {
    int row = blockIdx.x;
    const float* xr = x + (size_t)row * DM;
    int c0 = threadIdx.x * 4;
    float4 v = *(const float4*)&xr[c0];
    float s1 = v.x + v.y + v.z + v.w;
    float s2 = v.x*v.x + v.y*v.y + v.z*v.z + v.w*v.w;
#pragma unroll
    for (int off = 32; off > 0; off >>= 1) {
        s1 += __shfl_down(s1, off);
        s2 += __shfl_down(s2, off);
    }
    __shared__ float a1[4], a2[4];
    int wid = threadIdx.x >> 6;
    if ((threadIdx.x & 63) == 0) { a1[wid] = s1; a2[wid] = s2; }
    __syncthreads();
    s1 = a1[0] + a1[1] + a1[2] + a1[3];
    s2 = a2[0] + a2[1] + a2[2] + a2[3];
    float mu = s1 * (1.f/DM);
    float var = s2 * (1.f/DM) - mu*mu;
    float rstd = rsqrtf(var + 1e-5f);
    float o0 = (v.x - mu)*rstd*g[c0+0] + b[c0+0];
    float o1 = (v.y - mu)*rstd*g[c0+1] + b[c0+1];
    float o2 = (v.z - mu)*rstd*g[c0+2] + b[c0+2];
    float o3 = (v.w - mu)*rstd*g[c0+3] + b[c0+3];
    uint2 p; p.x = pack2(o0, o1); p.y = pack2(o2, o3);
    *(uint2*)&xbf[(size_t)row*DM + c0] = p;
}

// ---------------- fp32 -> bf16 weight conversion (grid-stride over float4) ----------------
__global__ __launch_bounds__(256) void cvt_bf16_kernel(const float* __restrict__ src,
        unsigned short* __restrict__ dst, int n4) {
    int i = blockIdx.x * 256 + threadIdx.x;
    if (i < n4) {
        float4 v = ((const float4*)src)[i];
        uint2 p; p.x = pack2(v.x, v.y); p.y = pack2(v.z, v.w);
        ((uint2*)dst)[i] = p;
    }
}

// ---------------- bf16 MFMA NT GEMM: C = (A @ W^T + bias) * scale ----------------
// A: M x K bf16 row-major; W: N x K bf16 row-major. 128x128 tile, BK=32,
// 4 waves each computing 64x64 via 4x4 grid of 16x16x32 MFMAs (m97 structure).
template<bool ROPE, bool OUTBF>
__global__ __launch_bounds__(256) void gemm_bf16(
        const unsigned short* __restrict__ A, const unsigned short* __restrict__ W,
        const float* __restrict__ bias, void* __restrict__ Cv,
        int N, int K, float scale) {
    __shared__ unsigned short As[128*32];
    __shared__ unsigned short Bs[128*32];
    const int tid = threadIdx.x;
    const int bm = blockIdx.y * 128;
    const int bn = blockIdx.x * 128;
    const int wave = tid >> 6, lane = tid & 63;
    const int wm = (wave & 1) * 64, wn = (wave >> 1) * 64;

    // staging: thread tid loads 16B (8 bf16); covers 64 rows x 32 cols per round
    const int srow = tid >> 2;
    const int scol = (tid & 3) * 8;
    const unsigned short* Ag = A + (size_t)(bm + srow) * K + scol;
    const unsigned short* Wg = W + (size_t)(bn + srow) * K + scol;

    // fragment addressing: lane holds op[r = lane&15][k = (lane>>4)*8 + j]
    const int fm = lane & 15, fk = (lane >> 4) * 8;

    floatx4 acc[4][4] = {};

    for (int k0 = 0; k0 < K; k0 += 32) {
        gld_lds16(Ag + k0,          &As[tid*8]);
        gld_lds16(Ag + (size_t)64*K + k0, &As[2048 + tid*8]);
        gld_lds16(Wg + k0,          &Bs[tid*8]);
        gld_lds16(Wg + (size_t)64*K + k0, &Bs[2048 + tid*8]);
        __syncthreads();
        short8 af[4], bf[4];
#pragma unroll
        for (int mi = 0; mi < 4; mi++)
            af[mi] = *(const short8*)&As[(wm + mi*16 + fm)*32 + fk];
#pragma unroll
        for (int ni = 0; ni < 4; ni++)
            bf[ni] = *(const short8*)&Bs[(wn + ni*16 + fm)*32 + fk];
#pragma unroll
        for (int mi = 0; mi < 4; mi++)
#pragma unroll
            for (int ni = 0; ni < 4; ni++)
                acc[mi][ni] = __builtin_amdgcn_mfma_f32_16x16x32_bf16(
                                  af[mi], bf[ni], acc[mi][ni], 0, 0, 0);
        __syncthreads();
    }

    // epilogue: C/D layout col=lane&15, row=(lane>>4)*4+reg
    const int crow = (lane >> 4) * 4;
    const int ccol = lane & 15;
    float* Cf = (float*)Cv;
    unsigned short* Cb = (unsigned short*)Cv;
#pragma unroll
    for (int mi = 0; mi < 4; mi++) {
#pragma unroll
        for (int ni = 0; ni < 4; ni++) {
            int col = bn + wn + ni*16 + ccol;
            float bcol = bias[col];
#pragma unroll
            for (int r = 0; r < 4; r++) {
                int row = bm + wm + mi*16 + crow + r;
                float v = (acc[mi][ni][r] + bcol) * scale;
                if (ROPE) {
                    float vp = __shfl_xor(v, 1);   // partner column (col ^ 1)
                    int s = row & (SEQ-1);
                    int jj = (col & 63) >> 1;
                    float ang = exp2f(-(float)jj * (13.287712379549449f/31.f));
                    float sn, cs;
                    sincosf((float)s * ang, &sn, &cs);
                    v = (col & 1) ? (v*cs + vp*sn) : (v*cs - vp*sn);
                }
                if (OUTBF) Cb[(size_t)row*N + col] = bfbits(v);
                else       Cf[(size_t)row*N + col] = v;
            }
        }
    }
}

// ---------------- retention per-chunk: inner_out (in-place over val), KV, inner_scale ----------------
__global__ __launch_bounds__(256) void ret_inner_kernel(
        const float* __restrict__ qry, const float* __restrict__ key,
        float* __restrict__ valio, float* __restrict__ kv_out,
        float* __restrict__ iscale_out) {
    int blk = blockIdx.x;           // (b*NH + h)*NC + c
    int c = blk & 63;
    int h = (blk >> 6) & 15;
    int b = blk >> 10;
    float dec = head_decay(h);

    __shared__ float uni[64*65];    // Q (stride 65) in phase 1, V half (stride 64) in phase 2
    __shared__ float Ks[CL][DK+1];
    __shared__ float Ss[CL][CL+1];
    __shared__ float ascale[CL];
    __shared__ float iscale[CL];

    int tid = threadIdx.x;
    size_t qkbase = ((size_t)(b*SEQ + c*CL))*DM + (size_t)h*DK;
#pragma unroll
    for (int t = 0; t < 16; t++) {
        int idx = tid + t*256;
        int i = idx >> 6, d = idx & 63;
        uni[i*65 + d] = qry[qkbase + (size_t)i*DM + d];
        Ks[i][d]      = key[qkbase + (size_t)i*DM + d];
    }
    if (tid < CL) {                 // attn_scale by explicit series (closed form cancels at h=15)
        float ssum = 0.f;
        for (int t = 0; t <= tid; t++) ssum += expf(dec * (float)t);
        ascale[tid] = sqrtf(ssum);
    }
    __syncthreads();

    // S = (Q @ K^T) * mask / ascale
    {
        int tx = tid & 15, ty = tid >> 4;
        float acc[4][4] = {};
        for (int d = 0; d < DK; d++) {
            float av[4], bv[4];
#pragma unroll
            for (int i = 0; i < 4; i++) av[i] = uni[(ty*4+i)*65 + d];
#pragma unroll
            for (int j = 0; j < 4; j++) bv[j] = Ks[tx*4+j][d];
#pragma unroll
            for (int i = 0; i < 4; i++)
#pragma unroll
                for (int j = 0; j < 4; j++)
                    acc[i][j] += av[i]*bv[j];
        }
#pragma unroll
        for (int i = 0; i < 4; i++) {
            int ri = ty*4 + i;
            float ra = 1.f / ascale[ri];
#pragma unroll
            for (int j = 0; j < 4; j++) {
                int cj = tx*4 + j;
                float m = (cj <= ri) ? expf(dec*(float)(ri-cj)) * ra : 0.f;
                Ss[ri][cj] = acc[i][j] * m;
            }
        }
    }
    __syncthreads();
    if (tid < CL) {                 // inner_scale = max(|row sum|, 1)
        float rs = 0.f;
        for (int j = 0; j < CL; j++) rs += Ss[tid][j];
        float isc = fmaxf(fabsf(rs), 1.f);
        iscale[tid] = isc;
        iscale_out[(size_t)blk*CL + tid] = isc;
    }

    // phase 2: (S/iscale)@V and K^T@V, V in two 64-col halves overlaying dead Q
    int txv = tid & 15, tyv = tid >> 4;
    int v0 = txv*4, i0 = tyv*4;
    size_t vbase = ((size_t)(b*SEQ + c*CL))*DG + (size_t)h*DV;
    for (int half = 0; half < 2; half++) {
        __syncthreads();            // prior uni readers done; iscale visible
#pragma unroll
        for (int t = 0; t < 16; t++) {
            int idx = tid + t*256;
            int i = idx >> 6, d = idx & 63;
            uni[i*64 + d] = valio[vbase + (size_t)i*DG + half*64 + d];
        }
        __syncthreads();
        float acc2[4][4] = {};
        float acc3[4][4] = {};
        for (int j = 0; j < CL; j++) {
            float4 vv = *(const float4*)&uni[j*64 + v0];
            float va[4] = {vv.x, vv.y, vv.z, vv.w};
#pragma unroll
            for (int r = 0; r < 4; r++) {
                float s  = Ss[i0+r][j];
                float kk = Ks[j][i0+r];
#pragma unroll
                for (int q = 0; q < 4; q++) {
                    acc2[r][q] += s*va[q];
                    acc3[r][q] += kk*va[q];
                }
            }
        }
#pragma unroll
        for (int r = 0; r < 4; r++) {
            int i = i0 + r;
            float inv = 1.f / iscale[i];
            float4 o = make_float4(acc2[r][0]*inv, acc2[r][1]*inv,
                                   acc2[r][2]*inv, acc2[r][3]*inv);
            *(float4*)&valio[vbase + (size_t)i*DG + half*64 + v0] = o;   // own elements only
            float4 kvo = make_float4(acc3[r][0], acc3[r][1], acc3[r][2], acc3[r][3]);
            *(float4*)&kv_out[(size_t)blk*(DK*DV) + (size_t)i*DV + half*64 + v0] = kvo;
        }
    }
}

// ---------------- sequential scan over chunks (in-place KV -> cross_chunk) ----------------
__global__ __launch_bounds__(256) void ret_scan_kernel(float* __restrict__ kv,
        float* __restrict__ cscale_out) {
    int tid = threadIdx.x;
    int col = blockIdx.x*16 + ((tid >> 6) << 2) + (tid & 3);  // 0..4095
    int kp  = (tid >> 2) & 15;
    int v   = col & 127;
    int bh  = col >> 7;
    int h   = bh & 15;
    float dec = head_decay(h);
    float cdecay = expf(dec * (float)CL);
    float state[4] = {0.f, 0.f, 0.f, 0.f};
    float scale = 1.f;
    size_t base0 = (size_t)bh*NC*(DK*DV) + (size_t)(kp*4)*DV + v;
    float cur[4];
#pragma unroll
    for (int kk = 0; kk < 4; kk++) cur[kk] = kv[base0 + (size_t)kk*DV];
    for (int c = 0; c < NC; c++) {
        size_t base = base0 + (size_t)c*(DK*DV);
        float nxt[4];
        if (c+1 < NC) {             // software-pipelined next-chunk load
            size_t nb = base + (size_t)(DK*DV);
#pragma unroll
            for (int kk = 0; kk < 4; kk++) nxt[kk] = kv[nb + (size_t)kk*DV];
        }
        float inv = 1.f / scale;
#pragma unroll
        for (int kk = 0; kk < 4; kk++) kv[base + (size_t)kk*DV] = cur[kk]*inv;
        if (kp == 0) cscale_out[((size_t)bh*NC + c)*DV + v] = scale;
        float ssum = 0.f;
#pragma unroll
        for (int kk = 0; kk < 4; kk++) {
            state[kk] = state[kk]*cdecay + cur[kk];
            ssum += fabsf(state[kk]);
        }
        ssum += __shfl_xor(ssum, 4);
        ssum += __shfl_xor(ssum, 8);
        ssum += __shfl_xor(ssum, 16);
        ssum += __shfl_xor(ssum, 32);
        scale = fmaxf(ssum, 1.f);
        if (c+1 < NC) {
#pragma unroll
            for (int kk = 0; kk < 4; kk++) cur[kk] = nxt[kk];
        }
    }
}

// ---------------- cross_out + combine + groupnorm + silu(gate) -> bf16 acts ----------------
__global__ __launch_bounds__(256) void ret_cross_kernel(
        const float* __restrict__ qry, const float* __restrict__ cross_chunk,
        const float* __restrict__ valio, const float* __restrict__ iscale,
        const float* __restrict__ cscale, const unsigned short* __restrict__ gatebf,
        const float* __restrict__ gn_g, const float* __restrict__ gn_b,
        unsigned short* __restrict__ actbf) {
    int blk = blockIdx.x;
    int c = blk & 63, h = (blk >> 6) & 15, b = blk >> 10;
    float dec = head_decay(h);
    __shared__ float Qs[CL][DK+1];
    __shared__ float CC[DK][DV];
    __shared__ float asc[CL];
    __shared__ float idec[CL];

    int tid = threadIdx.x;
    size_t qbase = ((size_t)(b*SEQ + c*CL))*DM + (size_t)h*DK;
#pragma unroll
    for (int t = 0; t < 16; t++) {
        int idx = tid + t*256;
        int i = idx >> 6, d = idx & 63;
        Qs[i][d] = qry[qbase + (size_t)i*DM + d];
    }
    size_t cbase = (size_t)blk * (DK*DV);
#pragma unroll
    for (int t = 0; t < 32; t++) {
        int idx = tid + t*256;
        CC[idx >> 7][idx & 127] = cross_chunk[cbase + idx];
    }
    if (tid < CL) {
        float ssum = 0.f;
        for (int t = 0; t <= tid; t++) ssum += expf(dec * (float)t);
        asc[tid] = sqrtf(ssum);
    }
    __syncthreads();
    if (tid < CL) idec[tid] = expf(dec*(float)(tid+1)) * asc[CL-1] / asc[tid];
    __syncthreads();

    int txv = tid & 31, tyv = tid >> 5;
    int v0 = txv*4, i0 = tyv*8;
    float acc[8][4] = {};
    for (int k = 0; k < DK; k++) {
        float4 cv = *(const float4*)&CC[k][v0];
        float ca[4] = {cv.x, cv.y, cv.z, cv.w};
#pragma unroll
        for (int r = 0; r < 8; r++) {
            float qv = Qs[i0+r][k];
#pragma unroll
            for (int q = 0; q < 4; q++) acc[r][q] += qv*ca[q];
        }
    }
    float4 csv = *(const float4*)&cscale[(size_t)blk*DV + v0];
    float csa[4] = {csv.x, csv.y, csv.z, csv.w};
    float o[8][4];
    float s1[8], s2[8];
#pragma unroll
    for (int r = 0; r < 8; r++) {
        int i = i0 + r;
        float f2 = idec[i] / iscale[(size_t)blk*CL + i];
        size_t orow = ((size_t)(b*SEQ + c*CL + i))*DG + (size_t)h*DV + v0;
        float4 io = *(const float4*)&valio[orow];
        float ioa[4] = {io.x, io.y, io.z, io.w};
        float rs1 = 0.f, rs2 = 0.f;
#pragma unroll
        for (int q = 0; q < 4; q++) {
            float ov = ioa[q]/csa[q] + acc[r][q]*f2;
            o[r][q] = ov;
            rs1 += ov; rs2 += ov*ov;
        }
        s1[r] = rs1; s2[r] = rs2;
    }
    // groupnorm over the head's 128 v's: reduce across 32 txv lanes
#pragma unroll
    for (int r = 0; r < 8; r++) {
#pragma unroll
        for (int m = 1; m <= 16; m <<= 1) {
            s1[r] += __shfl_xor(s1[r], m);
            s2[r] += __shfl_xor(s2[r], m);
        }
    }
#pragma unroll
    for (int r = 0; r < 8; r++) {
        int i = i0 + r;
        float mu = s1[r] * (1.f/DV);
        float var = s2[r] * (1.f/DV) - mu*mu;
        float rstd = rsqrtf(var + 1e-5f);
        size_t orow = ((size_t)(b*SEQ + c*CL + i))*DG + (size_t)h*DV + v0;
        uint2 gu = *(const uint2*)&gatebf[orow];
        float ga[4] = { bf2f((unsigned short)(gu.x & 0xffff)),
                        bf2f((unsigned short)(gu.x >> 16)),
                        bf2f((unsigned short)(gu.y & 0xffff)),
                        bf2f((unsigned short)(gu.y >> 16)) };
        float res[4];
#pragma unroll
        for (int q = 0; q < 4; q++) {
            int col = h*DV + v0 + q;
            float xn = (o[r][q] - mu)*rstd*gn_g[col] + gn_b[col];
            float sg = ga[q] / (1.f + expf(-ga[q]));
            res[q] = xn * sg;
        }
        uint2 p; p.x = pack2(res[0], res[1]); p.y = pack2(res[2], res[3]);
        *(uint2*)&actbf[orow] = p;
    }
}

extern "C" void kernel_launch(void* const* d_in, const int* in_sizes, int n_in,
                              void* d_out, int out_size, void* d_ws, size_t ws_size,
                              hipStream_t stream) {
    (void)in_sizes; (void)n_in; (void)out_size; (void)ws_size;
    const float* x    = (const float*)d_in[0];
    const float* W_q  = (const float*)d_in[2];
    const float* b_q  = (const float*)d_in[3];
    const float* W_k  = (const float*)d_in[4];
    const float* b_k  = (const float*)d_in[5];
    const float* W_v  = (const float*)d_in[6];
    const float* b_v  = (const float*)d_in[7];
    const float* W_g  = (const float*)d_in[8];
    const float* b_g  = (const float*)d_in[9];
    const float* W_o  = (const float*)d_in[10];
    const float* b_o  = (const float*)d_in[11];
    const float* ln_g = (const float*)d_in[12];
    const float* ln_b = (const float*)d_in[13];
    const float* gn_g = (const float*)d_in[14];
    const float* gn_b = (const float*)d_in[15];
    float* out = (float*)d_out;
    float* ws  = (float*)d_ws;

    // workspace layout (floats) — total 51,773,440 floats = 207.1 MB
    float* key    = ws;                       //  8,388,608 fp32 key; actbf (bf16, same bytes) after ret_inner
    float* valio  = key    + 8388608;         // 16,777,216 fp32: val -> inner_out
    float* kvbuf  = valio  + 16777216;        // 16,777,216 fp32: KV -> cross_chunk; xbf+W*bf aliased pre-ret
    float* gateb  = kvbuf  + 16777216;        //  8,388,608 floats = 16.7M bf16 gate
    float* iscale = gateb  + 8388608;         //    131,072
    float* cscale = iscale + 131072;          //    262,144
    float* wobuf  = cscale + 262144;          //  1,048,576 floats = 2M bf16 W_o
    float* qry    = out;                      // d_out doubles as qry scratch (dead before final GEMM)

    // bf16 views aliased over kvbuf (dead before ret_inner writes kvbuf)
    unsigned short* xbf   = (unsigned short*)kvbuf;            // 8,388,608 bf16
    unsigned short* Wq_bf = (unsigned short*)(kvbuf + 4194304);  // 1,048,576 bf16
    unsigned short* Wk_bf = (unsigned short*)(kvbuf + 4718592);
    unsigned short* Wv_bf = (unsigned short*)(kvbuf + 5242880);  // 2,097,152 bf16
    unsigned short* Wg_bf = (unsigned short*)(kvbuf + 6291456);
    unsigned short* Wo_bf = (unsigned short*)wobuf;
    unsigned short* gatebf = (unsigned short*)gateb;
    unsigned short* actbf  = (unsigned short*)key;

    ln_cvt_kernel<<<ROWS, 256, 0, stream>>>(x, ln_g, ln_b, xbf);
    cvt_bf16_kernel<<<(DM*DM/4 + 255)/256, 256, 0, stream>>>(W_q, Wq_bf, DM*DM/4);
    cvt_bf16_kernel<<<(DM*DM/4 + 255)/256, 256, 0, stream>>>(W_k, Wk_bf, DM*DM/4);
    cvt_bf16_kernel<<<(DG*DM/4 + 255)/256, 256, 0, stream>>>(W_v, Wv_bf, DG*DM/4);
    cvt_bf16_kernel<<<(DG*DM/4 + 255)/256, 256, 0, stream>>>(W_g, Wg_bf, DG*DM/4);
    cvt_bf16_kernel<<<(DM*DG/4 + 255)/256, 256, 0, stream>>>(W_o, Wo_bf, DM*DG/4);

    dim3 gq(DM/128, ROWS/128);   // 8 x 64
    dim3 gv(DG/128, ROWS/128);   // 16 x 64
    gemm_bf16<true,false ><<<gq, 256, 0, stream>>>(xbf, Wq_bf, b_q, qry,   DM, DM, 1.f);
    gemm_bf16<true,false ><<<gq, 256, 0, stream>>>(xbf, Wk_bf, b_k, key,   DM, DM, 0.125f);
    gemm_bf16<false,false><<<gv, 256, 0, stream>>>(xbf, Wv_bf, b_v, valio, DG, DM, 1.f);
    gemm_bf16<false,true ><<<gv, 256, 0, stream>>>(xbf, Wg_bf, b_g, gatebf, DG, DM, 1.f);

    ret_inner_kernel<<<BATCH*NH*NC, 256, 0, stream>>>(qry, key, valio, kvbuf, iscale);
    ret_scan_kernel<<<256, 256, 0, stream>>>(kvbuf, cscale);
    ret_cross_kernel<<<BATCH*NH*NC, 256, 0, stream>>>(qry, kvbuf, valio, iscale, cscale,
                                                      gatebf, gn_g, gn_b, actbf);

    gemm_bf16<false,false><<<gq, 256, 0, stream>>>(actbf, Wo_bf, b_o, out, DM, DG, 1.f);
}

// Round 4
// 1092.546 us; speedup vs baseline: 2.0987x; 1.1149x over previous
//
#include <hip/hip_runtime.h>
#include <hip/hip_bf16.h>
#include <math.h>

#define BATCH 2
#define SEQ 4096
#define DM 1024
#define NH 16
#define DK 64
#define DV 128
#define NC 64     // number of chunks
#define CL 64     // chunk length
#define ROWS (BATCH*SEQ)   // 8192
#define DG (DM*2)          // 2048 (val/gate width)

typedef __attribute__((ext_vector_type(8))) short short8;
typedef __attribute__((ext_vector_type(4))) float floatx4;

__device__ __forceinline__ float head_decay(int h) {
    return logf(1.0f - exp2f(-5.0f - (float)h));
}
__device__ __forceinline__ unsigned short bfbits(float v) {
    __hip_bfloat16 h = __float2bfloat16(v);
    return *(unsigned short*)&h;
}
__device__ __forceinline__ float bf2f(unsigned short u) {
    unsigned x = ((unsigned)u) << 16;
    return *(float*)&x;
}
__device__ __forceinline__ unsigned pack2(float a, float b) {
    return (unsigned)bfbits(a) | ((unsigned)bfbits(b) << 16);
}
__device__ __forceinline__ void gld_lds16(const unsigned short* g, unsigned short* l) {
    __builtin_amdgcn_global_load_lds(
        (const __attribute__((address_space(1))) unsigned int*)g,
        (__attribute__((address_space(3))) unsigned int*)l, 16, 0, 0);
}

// ---------------- LN + cast to bf16: one block per row ----------------
__global__ __launch_bounds__(256) void ln_cvt_kernel(const float* __restrict__ x,
        const float* __restrict__ g, const float* __restrict__ b,
        unsigned short* __restrict__ xbf) {
    int row = blockIdx.x;
    const float* xr = x + (size_t)row * DM;
    int c0 = threadIdx.x * 4;
    float4 v = *(const float4*)&xr[c0];
    float s1 = v.x + v.y + v.z + v.w;
    float s2 = v.x*v.x + v.y*v.y + v.z*v.z + v.w*v.w;
#pragma unroll
    for (int off = 32; off > 0; off >>= 1) {
        s1 += __shfl_down(s1, off);
        s2 += __shfl_down(s2, off);
    }
    __shared__ float a1[4], a2[4];
    int wid = threadIdx.x >> 6;
    if ((threadIdx.x & 63) == 0) { a1[wid] = s1; a2[wid] = s2; }
    __syncthreads();
    s1 = a1[0] + a1[1] + a1[2] + a1[3];
    s2 = a2[0] + a2[1] + a2[2] + a2[3];
    float mu = s1 * (1.f/DM);
    float var = s2 * (1.f/DM) - mu*mu;
    float rstd = rsqrtf(var + 1e-5f);
    float o0 = (v.x - mu)*rstd*g[c0+0] + b[c0+0];
    float o1 = (v.y - mu)*rstd*g[c0+1] + b[c0+1];
    float o2 = (v.z - mu)*rstd*g[c0+2] + b[c0+2];
    float o3 = (v.w - mu)*rstd*g[c0+3] + b[c0+3];
    uint2 p; p.x = pack2(o0, o1); p.y = pack2(o2, o3);
    *(uint2*)&xbf[(size_t)row*DM + c0] = p;
}

// ---------------- fp32 -> bf16 weight conversion (grid-stride over float4) ----------------
__global__ __launch_bounds__(256) void cvt_bf16_kernel(const float* __restrict__ src,
        unsigned short* __restrict__ dst, int n4) {
    int i = blockIdx.x * 256 + threadIdx.x;
    if (i < n4) {
        float4 v = ((const float4*)src)[i];
        uint2 p; p.x = pack2(v.x, v.y); p.y = pack2(v.z, v.w);
        ((uint2*)dst)[i] = p;
    }
}

// ---------------- bf16 MFMA NT GEMM: C = (A @ W^T + bias) * scale ----------------
// A: M x K bf16 row-major; W: N x K bf16 row-major. 128x128 tile, BK=32,
// 4 waves each computing 64x64 via 4x4 grid of 16x16x32 MFMAs (m97 structure).
// 1D grid with XCD-aware grouped rasterization:
//   logical = (id%8)*(nb/8) + id/8  -> each XCD (round-robin by id) owns a
//   contiguous logical range; within it, groups of 8 pm x nbn pn keep the
//   concurrent working set (~8 A-tiles + W-tiles) inside the 4 MB per-XCD L2.
template<bool ROPE, bool OUTBF>
__global__ __launch_bounds__(256) void gemm_bf16(
        const unsigned short* __restrict__ A, const unsigned short* __restrict__ W,
        const float* __restrict__ bias, void* __restrict__ Cv,
        int N, int K, float scale) {
    const int nbn = N >> 7;
    const int nbm = ROWS >> 7;          // 64
    const int nb  = nbm * nbn;
    const int per = nb >> 3;            // blocks per XCD
    int id = blockIdx.x;
    int logical = (id & 7) * per + (id >> 3);
    const int in_grp = 8 * nbn;         // GROUP=8 pm-rows per stripe
    int g   = logical / in_grp;
    int rem = logical - g * in_grp;
    int pm  = g * 8 + (rem & 7);
    int pn  = rem >> 3;
    const int bm = pm * 128;
    const int bn = pn * 128;

    __shared__ unsigned short As[128*32];
    __shared__ unsigned short Bs[128*32];
    const int tid = threadIdx.x;
    const int wave = tid >> 6, lane = tid & 63;
    const int wm = (wave & 1) * 64, wn = (wave >> 1) * 64;

    // staging: thread tid loads 16B (8 bf16); covers 64 rows x 32 cols per round
    const int srow = tid >> 2;
    const int scol = (tid & 3) * 8;
    const unsigned short* Ag = A + (size_t)(bm + srow) * K + scol;
    const unsigned short* Wg = W + (size_t)(bn + srow) * K + scol;

    // fragment addressing: lane holds op[r = lane&15][k = (lane>>4)*8 + j]
    const int fm = lane & 15, fk = (lane >> 4) * 8;

    floatx4 acc[4][4] = {};

    for (int k0 = 0; k0 < K; k0 += 32) {
        gld_lds16(Ag + k0,                &As[tid*8]);
        gld_lds16(Ag + (size_t)64*K + k0, &As[2048 + tid*8]);
        gld_lds16(Wg + k0,                &Bs[tid*8]);
        gld_lds16(Wg + (size_t)64*K + k0, &Bs[2048 + tid*8]);
        __syncthreads();
        short8 af[4], bf[4];
#pragma unroll
        for (int mi = 0; mi < 4; mi++)
            af[mi] = *(const short8*)&As[(wm + mi*16 + fm)*32 + fk];
#pragma unroll
        for (int ni = 0; ni < 4; ni++)
            bf[ni] = *(const short8*)&Bs[(wn + ni*16 + fm)*32 + fk];
#pragma unroll
        for (int mi = 0; mi < 4; mi++)
#pragma unroll
            for (int ni = 0; ni < 4; ni++)
                acc[mi][ni] = __builtin_amdgcn_mfma_f32_16x16x32_bf16(
                                  af[mi], bf[ni], acc[mi][ni], 0, 0, 0);
        __syncthreads();
    }

    // epilogue: C/D layout col=lane&15, row=(lane>>4)*4+reg
    const int crow = (lane >> 4) * 4;
    const int ccol = lane & 15;
    float* Cf = (float*)Cv;
    unsigned short* Cb = (unsigned short*)Cv;
#pragma unroll
    for (int mi = 0; mi < 4; mi++) {
#pragma unroll
        for (int ni = 0; ni < 4; ni++) {
            int col = bn + wn + ni*16 + ccol;
            float bcol = bias[col];
#pragma unroll
            for (int r = 0; r < 4; r++) {
                int row = bm + wm + mi*16 + crow + r;
                float v = (acc[mi][ni][r] + bcol) * scale;
                if (ROPE) {
                    float vp = __shfl_xor(v, 1);   // partner column (col ^ 1)
                    int s = row & (SEQ-1);
                    int jj = (col & 63) >> 1;
                    float ang = exp2f(-(float)jj * (13.287712379549449f/31.f));
                    float sn, cs;
                    sincosf((float)s * ang, &sn, &cs);
                    v = (col & 1) ? (v*cs + vp*sn) : (v*cs - vp*sn);
                }
                if (OUTBF) Cb[(size_t)row*N + col] = bfbits(v);
                else       Cf[(size_t)row*N + col] = v;
            }
        }
    }
}

// ---------------- retention per-chunk: inner_out (in-place over val), KV, inner_scale ----------------
__global__ __launch_bounds__(256) void ret_inner_kernel(
        const float* __restrict__ qry, const float* __restrict__ key,
        float* __restrict__ valio, float* __restrict__ kv_out,
        float* __restrict__ iscale_out) {
    int blk = blockIdx.x;           // (b*NH + h)*NC + c
    int c = blk & 63;
    int h = (blk >> 6) & 15;
    int b = blk >> 10;
    float dec = head_decay(h);

    __shared__ float uni[64*65];    // Q (stride 65) in phase 1, V half (stride 64) in phase 2
    __shared__ float Ks[CL][DK+1];
    __shared__ float Ss[CL][CL+1];
    __shared__ float ascale[CL];
    __shared__ float iscale[CL];

    int tid = threadIdx.x;
    size_t qkbase = ((size_t)(b*SEQ + c*CL))*DM + (size_t)h*DK;
#pragma unroll
    for (int t = 0; t < 16; t++) {
        int idx = tid + t*256;
        int i = idx >> 6, d = idx & 63;
        uni[i*65 + d] = qry[qkbase + (size_t)i*DM + d];
        Ks[i][d]      = key[qkbase + (size_t)i*DM + d];
    }
    if (tid < CL) {                 // attn_scale by explicit series (closed form cancels at h=15)
        float ssum = 0.f;
        for (int t = 0; t <= tid; t++) ssum += expf(dec * (float)t);
        ascale[tid] = sqrtf(ssum);
    }
    __syncthreads();

    // S = (Q @ K^T) * mask / ascale
    {
        int tx = tid & 15, ty = tid >> 4;
        float acc[4][4] = {};
        for (int d = 0; d < DK; d++) {
            float av[4], bv[4];
#pragma unroll
            for (int i = 0; i < 4; i++) av[i] = uni[(ty*4+i)*65 + d];
#pragma unroll
            for (int j = 0; j < 4; j++) bv[j] = Ks[tx*4+j][d];
#pragma unroll
            for (int i = 0; i < 4; i++)
#pragma unroll
                for (int j = 0; j < 4; j++)
                    acc[i][j] += av[i]*bv[j];
        }
#pragma unroll
        for (int i = 0; i < 4; i++) {
            int ri = ty*4 + i;
            float ra = 1.f / ascale[ri];
#pragma unroll
            for (int j = 0; j < 4; j++) {
                int cj = tx*4 + j;
                float m = (cj <= ri) ? expf(dec*(float)(ri-cj)) * ra : 0.f;
                Ss[ri][cj] = acc[i][j] * m;
            }
        }
    }
    __syncthreads();
    if (tid < CL) {                 // inner_scale = max(|row sum|, 1)
        float rs = 0.f;
        for (int j = 0; j < CL; j++) rs += Ss[tid][j];
        float isc = fmaxf(fabsf(rs), 1.f);
        iscale[tid] = isc;
        iscale_out[(size_t)blk*CL + tid] = isc;
    }

    // phase 2: (S/iscale)@V and K^T@V, V in two 64-col halves overlaying dead Q
    int txv = tid & 15, tyv = tid >> 4;
    int v0 = txv*4, i0 = tyv*4;
    size_t vbase = ((size_t)(b*SEQ + c*CL))*DG + (size_t)h*DV;
    for (int half = 0; half < 2; half++) {
        __syncthreads();            // prior uni readers done; iscale visible
#pragma unroll
        for (int t = 0; t < 16; t++) {
            int idx = tid + t*256;
            int i = idx >> 6, d = idx & 63;
            uni[i*64 + d] = valio[vbase + (size_t)i*DG + half*64 + d];
        }
        __syncthreads();
        float acc2[4][4] = {};
        float acc3[4][4] = {};
        for (int j = 0; j < CL; j++) {
            float4 vv = *(const float4*)&uni[j*64 + v0];
            float va[4] = {vv.x, vv.y, vv.z, vv.w};
#pragma unroll
            for (int r = 0; r < 4; r++) {
                float s  = Ss[i0+r][j];
                float kk = Ks[j][i0+r];
#pragma unroll
                for (int q = 0; q < 4; q++) {
                    acc2[r][q] += s*va[q];
                    acc3[r][q] += kk*va[q];
                }
            }
        }
#pragma unroll
        for (int r = 0; r < 4; r++) {
            int i = i0 + r;
            float inv = 1.f / iscale[i];
            float4 o = make_float4(acc2[r][0]*inv, acc2[r][1]*inv,
                                   acc2[r][2]*inv, acc2[r][3]*inv);
            *(float4*)&valio[vbase + (size_t)i*DG + half*64 + v0] = o;   // own elements only
            float4 kvo = make_float4(acc3[r][0], acc3[r][1], acc3[r][2], acc3[r][3]);
            *(float4*)&kv_out[(size_t)blk*(DK*DV) + (size_t)i*DV + half*64 + v0] = kvo;
        }
    }
}

// ---------------- sequential scan over chunks (in-place KV -> cross_chunk) ----------------
__global__ __launch_bounds__(256) void ret_scan_kernel(float* __restrict__ kv,
        float* __restrict__ cscale_out) {
    int tid = threadIdx.x;
    int col = blockIdx.x*16 + ((tid >> 6) << 2) + (tid & 3);  // 0..4095
    int kp  = (tid >> 2) & 15;
    int v   = col & 127;
    int bh  = col >> 7;
    int h   = bh & 15;
    float dec = head_decay(h);
    float cdecay = expf(dec * (float)CL);
    float state[4] = {0.f, 0.f, 0.f, 0.f};
    float scale = 1.f;
    size_t base0 = (size_t)bh*NC*(DK*DV) + (size_t)(kp*4)*DV + v;
    float cur[4];
#pragma unroll
    for (int kk = 0; kk < 4; kk++) cur[kk] = kv[base0 + (size_t)kk*DV];
    for (int c = 0; c < NC; c++) {
        size_t base = base0 + (size_t)c*(DK*DV);
        float nxt[4];
        if (c+1 < NC) {             // software-pipelined next-chunk load
            size_t nb = base + (size_t)(DK*DV);
#pragma unroll
            for (int kk = 0; kk < 4; kk++) nxt[kk] = kv[nb + (size_t)kk*DV];
        }
        float inv = 1.f / scale;
#pragma unroll
        for (int kk = 0; kk < 4; kk++) kv[base + (size_t)kk*DV] = cur[kk]*inv;
        if (kp == 0) cscale_out[((size_t)bh*NC + c)*DV + v] = scale;
        float ssum = 0.f;
#pragma unroll
        for (int kk = 0; kk < 4; kk++) {
            state[kk] = state[kk]*cdecay + cur[kk];
            ssum += fabsf(state[kk]);
        }
        ssum += __shfl_xor(ssum, 4);
        ssum += __shfl_xor(ssum, 8);
        ssum += __shfl_xor(ssum, 16);
        ssum += __shfl_xor(ssum, 32);
        scale = fmaxf(ssum, 1.f);
        if (c+1 < NC) {
#pragma unroll
            for (int kk = 0; kk < 4; kk++) cur[kk] = nxt[kk];
        }
    }
}

// ---------------- cross_out + combine + groupnorm + silu(gate) -> bf16 acts ----------------
__global__ __launch_bounds__(256) void ret_cross_kernel(
        const float* __restrict__ qry, const float* __restrict__ cross_chunk,
        const float* __restrict__ valio, const float* __restrict__ iscale,
        const float* __restrict__ cscale, const unsigned short* __restrict__ gatebf,
        const float* __restrict__ gn_g, const float* __restrict__ gn_b,
        unsigned short* __restrict__ actbf) {
    int blk = blockIdx.x;
    int c = blk & 63, h = (blk >> 6) & 15, b = blk >> 10;
    float dec = head_decay(h);
    __shared__ float Qs[CL][DK+1];
    __shared__ float CC[DK][DV];
    __shared__ float asc[CL];
    __shared__ float idec[CL];

    int tid = threadIdx.x;
    size_t qbase = ((size_t)(b*SEQ + c*CL))*DM + (size_t)h*DK;
#pragma unroll
    for (int t = 0; t < 16; t++) {
        int idx = tid + t*256;
        int i = idx >> 6, d = idx & 63;
        Qs[i][d] = qry[qbase + (size_t)i*DM + d];
    }
    size_t cbase = (size_t)blk * (DK*DV);
#pragma unroll
    for (int t = 0; t < 32; t++) {
        int idx = tid + t*256;
        CC[idx >> 7][idx & 127] = cross_chunk[cbase + idx];
    }
    if (tid < CL) {
        float ssum = 0.f;
        for (int t = 0; t <= tid; t++) ssum += expf(dec * (float)t);
        asc[tid] = sqrtf(ssum);
    }
    __syncthreads();
    if (tid < CL) idec[tid] = expf(dec*(float)(tid+1)) * asc[CL-1] / asc[tid];
    __syncthreads();

    int txv = tid & 31, tyv = tid >> 5;
    int v0 = txv*4, i0 = tyv*8;
    float acc[8][4] = {};
    for (int k = 0; k < DK; k++) {
        float4 cv = *(const float4*)&CC[k][v0];
        float ca[4] = {cv.x, cv.y, cv.z, cv.w};
#pragma unroll
        for (int r = 0; r < 8; r++) {
            float qv = Qs[i0+r][k];
#pragma unroll
            for (int q = 0; q < 4; q++) acc[r][q] += qv*ca[q];
        }
    }
    float4 csv = *(const float4*)&cscale[(size_t)blk*DV + v0];
    float csa[4] = {csv.x, csv.y, csv.z, csv.w};
    float o[8][4];
    float s1[8], s2[8];
#pragma unroll
    for (int r = 0; r < 8; r++) {
        int i = i0 + r;
        float f2 = idec[i] / iscale[(size_t)blk*CL + i];
        size_t orow = ((size_t)(b*SEQ + c*CL + i))*DG + (size_t)h*DV + v0;
        float4 io = *(const float4*)&valio[orow];
        float ioa[4] = {io.x, io.y, io.z, io.w};
        float rs1 = 0.f, rs2 = 0.f;
#pragma unroll
        for (int q = 0; q < 4; q++) {
            float ov = ioa[q]/csa[q] + acc[r][q]*f2;
            o[r][q] = ov;
            rs1 += ov; rs2 += ov*ov;
        }
        s1[r] = rs1; s2[r] = rs2;
    }
    // groupnorm over the head's 128 v's: reduce across 32 txv lanes
#pragma unroll
    for (int r = 0; r < 8; r++) {
#pragma unroll
        for (int m = 1; m <= 16; m <<= 1) {
            s1[r] += __shfl_xor(s1[r], m);
            s2[r] += __shfl_xor(s2[r], m);
        }
    }
#pragma unroll
    for (int r = 0; r < 8; r++) {
        int i = i0 + r;
        float mu = s1[r] * (1.f/DV);
        float var = s2[r] * (1.f/DV) - mu*mu;
        float rstd = rsqrtf(var + 1e-5f);
        size_t orow = ((size_t)(b*SEQ + c*CL + i))*DG + (size_t)h*DV + v0;
        uint2 gu = *(const uint2*)&gatebf[orow];
        float ga[4] = { bf2f((unsigned short)(gu.x & 0xffff)),
                        bf2f((unsigned short)(gu.x >> 16)),
                        bf2f((unsigned short)(gu.y & 0xffff)),
                        bf2f((unsigned short)(gu.y >> 16)) };
        float res[4];
#pragma unroll
        for (int q = 0; q < 4; q++) {
            int col = h*DV + v0 + q;
            float xn = (o[r][q] - mu)*rstd*gn_g[col] + gn_b[col];
            float sg = ga[q] / (1.f + expf(-ga[q]));
            res[q] = xn * sg;
        }
        uint2 p; p.x = pack2(res[0], res[1]); p.y = pack2(res[2], res[3]);
        *(uint2*)&actbf[orow] = p;
    }
}

extern "C" void kernel_launch(void* const* d_in, const int* in_sizes, int n_in,
                              void* d_out, int out_size, void* d_ws, size_t ws_size,
                              hipStream_t stream) {
    (void)in_sizes; (void)n_in; (void)out_size; (void)ws_size;
    const float* x    = (const float*)d_in[0];
    const float* W_q  = (const float*)d_in[2];
    const float* b_q  = (const float*)d_in[3];
    const float* W_k  = (const float*)d_in[4];
    const float* b_k  = (const float*)d_in[5];
    const float* W_v  = (const float*)d_in[6];
    const float* b_v  = (const float*)d_in[7];
    const float* W_g  = (const float*)d_in[8];
    const float* b_g  = (const float*)d_in[9];
    const float* W_o  = (const float*)d_in[10];
    const float* b_o  = (const float*)d_in[11];
    const float* ln_g = (const float*)d_in[12];
    const float* ln_b = (const float*)d_in[13];
    const float* gn_g = (const float*)d_in[14];
    const float* gn_b = (const float*)d_in[15];
    float* out = (float*)d_out;
    float* ws  = (float*)d_ws;

    // workspace layout (floats) — total 51,773,440 floats = 207.1 MB
    float* key    = ws;                       //  8,388,608 fp32 key; actbf (bf16, same bytes) after ret_inner
    float* valio  = key    + 8388608;         // 16,777,216 fp32: val -> inner_out
    float* kvbuf  = valio  + 16777216;        // 16,777,216 fp32: KV -> cross_chunk; xbf+W*bf aliased pre-ret
    float* gateb  = kvbuf  + 16777216;        //  8,388,608 floats = 16.7M bf16 gate
    float* iscale = gateb  + 8388608;         //    131,072
    float* cscale = iscale + 131072;          //    262,144
    float* wobuf  = cscale + 262144;          //  1,048,576 floats = 2M bf16 W_o
    float* qry    = out;                      // d_out doubles as qry scratch (dead before final GEMM)

    // bf16 views aliased over kvbuf (dead before ret_inner writes kvbuf)
    unsigned short* xbf   = (unsigned short*)kvbuf;            // 8,388,608 bf16
    unsigned short* Wq_bf = (unsigned short*)(kvbuf + 4194304);  // 1,048,576 bf16
    unsigned short* Wk_bf = (unsigned short*)(kvbuf + 4718592);
    unsigned short* Wv_bf = (unsigned short*)(kvbuf + 5242880);  // 2,097,152 bf16
    unsigned short* Wg_bf = (unsigned short*)(kvbuf + 6291456);
    unsigned short* Wo_bf = (unsigned short*)wobuf;
    unsigned short* gatebf = (unsigned short*)gateb;
    unsigned short* actbf  = (unsigned short*)key;

    ln_cvt_kernel<<<ROWS, 256, 0, stream>>>(x, ln_g, ln_b, xbf);
    cvt_bf16_kernel<<<(DM*DM/4 + 255)/256, 256, 0, stream>>>(W_q, Wq_bf, DM*DM/4);
    cvt_bf16_kernel<<<(DM*DM/4 + 255)/256, 256, 0, stream>>>(W_k, Wk_bf, DM*DM/4);
    cvt_bf16_kernel<<<(DG*DM/4 + 255)/256, 256, 0, stream>>>(W_v, Wv_bf, DG*DM/4);
    cvt_bf16_kernel<<<(DG*DM/4 + 255)/256, 256, 0, stream>>>(W_g, Wg_bf, DG*DM/4);
    cvt_bf16_kernel<<<(DM*DG/4 + 255)/256, 256, 0, stream>>>(W_o, Wo_bf, DM*DG/4);

    const int nbq = (DM/128) * (ROWS/128);   // 512
    const int nbv = (DG/128) * (ROWS/128);   // 1024
    gemm_bf16<true,false ><<<nbq, 256, 0, stream>>>(xbf, Wq_bf, b_q, qry,   DM, DM, 1.f);
    gemm_bf16<true,false ><<<nbq, 256, 0, stream>>>(xbf, Wk_bf, b_k, key,   DM, DM, 0.125f);
    gemm_bf16<false,false><<<nbv, 256, 0, stream>>>(xbf, Wv_bf, b_v, valio, DG, DM, 1.f);
    gemm_bf16<false,true ><<<nbv, 256, 0, stream>>>(xbf, Wg_bf, b_g, gatebf, DG, DM, 1.f);

    ret_inner_kernel<<<BATCH*NH*NC, 256, 0, stream>>>(qry, key, valio, kvbuf, iscale);
    ret_scan_kernel<<<256, 256, 0, stream>>>(kvbuf, cscale);
    ret_cross_kernel<<<BATCH*NH*NC, 256, 0, stream>>>(qry, kvbuf, valio, iscale, cscale,
                                                      gatebf, gn_g, gn_b, actbf);

    gemm_bf16<false,false><<<nbq, 256, 0, stream>>>(actbf, Wo_bf, b_o, out, DM, DG, 1.f);
}

// Round 5
// 698.650 us; speedup vs baseline: 3.2820x; 1.5638x over previous
//
#include <hip/hip_runtime.h>
#include <hip/hip_bf16.h>
#include <math.h>

#define BATCH 2
#define SEQ 4096
#define DM 1024
#define NH 16
#define DK 64
#define DV 128
#define NC 64     // number of chunks
#define CL 64     // chunk length
#define ROWS (BATCH*SEQ)   // 8192
#define DG (DM*2)          // 2048 (val/gate width)

typedef __attribute__((ext_vector_type(8))) short short8;
typedef __attribute__((ext_vector_type(4))) float floatx4;

__device__ __forceinline__ float head_decay(int h) {
    return logf(1.0f - exp2f(-5.0f - (float)h));
}
__device__ __forceinline__ unsigned short bfbits(float v) {
    __hip_bfloat16 h = __float2bfloat16(v);
    return *(unsigned short*)&h;
}
__device__ __forceinline__ float bf2f(unsigned short u) {
    unsigned x = ((unsigned)u) << 16;
    return *(float*)&x;
}
__device__ __forceinline__ unsigned pack2(float a, float b) {
    return (unsigned)bfbits(a) | ((unsigned)bfbits(b) << 16);
}
__device__ __forceinline__ void unpack8(uint4 u, float* dst) {
    dst[0]=bf2f((unsigned short)(u.x&0xffff)); dst[1]=bf2f((unsigned short)(u.x>>16));
    dst[2]=bf2f((unsigned short)(u.y&0xffff)); dst[3]=bf2f((unsigned short)(u.y>>16));
    dst[4]=bf2f((unsigned short)(u.z&0xffff)); dst[5]=bf2f((unsigned short)(u.z>>16));
    dst[6]=bf2f((unsigned short)(u.w&0xffff)); dst[7]=bf2f((unsigned short)(u.w>>16));
}
__device__ __forceinline__ void gld_lds16(const unsigned short* g, unsigned short* l) {
    __builtin_amdgcn_global_load_lds(
        (const __attribute__((address_space(1))) unsigned int*)g,
        (__attribute__((address_space(3))) unsigned int*)l, 16, 0, 0);
}

// ---------------- LN + cast to bf16: one block per row ----------------
__global__ __launch_bounds__(256) void ln_cvt_kernel(const float* __restrict__ x,
        const float* __restrict__ g, const float* __restrict__ b,
        unsigned short* __restrict__ xbf) {
    int row = blockIdx.x;
    const float* xr = x + (size_t)row * DM;
    int c0 = threadIdx.x * 4;
    float4 v = *(const float4*)&xr[c0];
    float s1 = v.x + v.y + v.z + v.w;
    float s2 = v.x*v.x + v.y*v.y + v.z*v.z + v.w*v.w;
#pragma unroll
    for (int off = 32; off > 0; off >>= 1) {
        s1 += __shfl_down(s1, off);
        s2 += __shfl_down(s2, off);
    }
    __shared__ float a1[4], a2[4];
    int wid = threadIdx.x >> 6;
    if ((threadIdx.x & 63) == 0) { a1[wid] = s1; a2[wid] = s2; }
    __syncthreads();
    s1 = a1[0] + a1[1] + a1[2] + a1[3];
    s2 = a2[0] + a2[1] + a2[2] + a2[3];
    float mu = s1 * (1.f/DM);
    float var = s2 * (1.f/DM) - mu*mu;
    float rstd = rsqrtf(var + 1e-5f);
    float o0 = (v.x - mu)*rstd*g[c0+0] + b[c0+0];
    float o1 = (v.y - mu)*rstd*g[c0+1] + b[c0+1];
    float o2 = (v.z - mu)*rstd*g[c0+2] + b[c0+2];
    float o3 = (v.w - mu)*rstd*g[c0+3] + b[c0+3];
    uint2 p; p.x = pack2(o0, o1); p.y = pack2(o2, o3);
    *(uint2*)&xbf[(size_t)row*DM + c0] = p;
}

// ---------------- fp32 -> bf16 weight conversion ----------------
__global__ __launch_bounds__(256) void cvt_bf16_kernel(const float* __restrict__ src,
        unsigned short* __restrict__ dst, int n4) {
    int i = blockIdx.x * 256 + threadIdx.x;
    if (i < n4) {
        float4 v = ((const float4*)src)[i];
        uint2 p; p.x = pack2(v.x, v.y); p.y = pack2(v.z, v.w);
        ((uint2*)dst)[i] = p;
    }
}

// ---------------- bf16 MFMA NT GEMM, 128x128 tile, BK=32, m97 staging ----------------
// QKVG=true: A(8192x1024) x Wcat(6144x1024)^T; per-segment epilogue
//   seg0 Q->o0(bf16,N=1024,rope) seg1 K->o1(bf16,rope,scale .125)
//   seg2,3 V->o2(bf16,N=2048) seg4,5 G->o3(bf16,N=2048)
// QKVG=false: A x W^T + b0 -> o0 (fp32, N=Ntot)
// Epilogue routes accumulators through LDS so global stores are contiguous
// 256B(bf16)/512B(fp32) row runs -> full-line writes (kills the 17x write amp).
// 1D grid, XCD-aware raster: xcd owns pm stripe of 8, pn sweeps.
template<bool QKVG>
__global__ __launch_bounds__(256) void gemm_mfma(
        const unsigned short* __restrict__ A, const unsigned short* __restrict__ W,
        int K, int Ntot,
        const float* __restrict__ b0, const float* __restrict__ b1,
        const float* __restrict__ b2, const float* __restrict__ b3,
        void* __restrict__ o0, void* __restrict__ o1,
        void* __restrict__ o2, void* __restrict__ o3) {
    const int nbn = Ntot >> 7;
    const int nb  = (ROWS >> 7) * nbn;
    const int per = nb >> 3;
    int id = blockIdx.x;
    int logical = (id & 7) * per + (id >> 3);
    const int in_grp = 8 * nbn;
    int g   = logical / in_grp;
    int rem = logical - g * in_grp;
    const int bm = (g * 8 + (rem & 7)) << 7;
    const int bn = (rem >> 3) << 7;

    __shared__ unsigned short As[128*32];
    __shared__ unsigned short Bs[128*32];
    __shared__ float epi[32*128];          // 16 KB; bf16 path uses as 64x128 shorts

    const int tid = threadIdx.x;
    const int wave = tid >> 6, lane = tid & 63;
    const int wm = (wave & 1) * 64, wn = (wave >> 1) * 64;
    const int srow = tid >> 2, scol = (tid & 3) * 8;
    const unsigned short* Ag = A + (size_t)(bm + srow) * K + scol;
    const unsigned short* Wg = W + (size_t)(bn + srow) * K + scol;
    const int fm = lane & 15, fk = (lane >> 4) * 8;

    floatx4 acc[4][4] = {};
    for (int k0 = 0; k0 < K; k0 += 32) {
        gld_lds16(Ag + k0,                &As[tid*8]);
        gld_lds16(Ag + (size_t)64*K + k0, &As[2048 + tid*8]);
        gld_lds16(Wg + k0,                &Bs[tid*8]);
        gld_lds16(Wg + (size_t)64*K + k0, &Bs[2048 + tid*8]);
        __syncthreads();
        short8 af[4], bfv[4];
#pragma unroll
        for (int mi = 0; mi < 4; mi++)
            af[mi] = *(const short8*)&As[(wm + mi*16 + fm)*32 + fk];
#pragma unroll
        for (int ni = 0; ni < 4; ni++)
            bfv[ni] = *(const short8*)&Bs[(wn + ni*16 + fm)*32 + fk];
#pragma unroll
        for (int mi = 0; mi < 4; mi++)
#pragma unroll
            for (int ni = 0; ni < 4; ni++)
                acc[mi][ni] = __builtin_amdgcn_mfma_f32_16x16x32_bf16(
                                  af[mi], bfv[ni], acc[mi][ni], 0, 0, 0);
        __syncthreads();
    }

    // segment routing (block-uniform)
    float scale = 1.f; bool doRope = false;
    const float* bias; int No, lcb;
    unsigned short* obf = nullptr; float* of32 = nullptr;
    if (QKVG) {
        int seg = bn >> 10;
        if (seg == 0)      { obf = (unsigned short*)o0; bias = b0; No = 1024; lcb = bn;        doRope = true; }
        else if (seg == 1) { obf = (unsigned short*)o1; bias = b1; No = 1024; lcb = bn - 1024; doRope = true; scale = 0.125f; }
        else if (seg <= 3) { obf = (unsigned short*)o2; bias = b2; No = 2048; lcb = bn - 2048; }
        else               { obf = (unsigned short*)o3; bias = b3; No = 2048; lcb = bn - 4096; }
    } else {
        of32 = (float*)o0; bias = b0; No = Ntot; lcb = bn;
    }

    const int crow = (lane >> 4) * 4, ccol = lane & 15;
    unsigned short* epib = (unsigned short*)epi;
    const int RPP   = QKVG ? 64 : 32;     // rows per pass (16 KB LDS each)
    const int NPASS = 128 / RPP;

    for (int pass = 0; pass < NPASS; pass++) {
#pragma unroll
        for (int mi = 0; mi < 4; mi++) {
            if (((wm + mi*16) / RPP) != pass) continue;   // wave-uniform
#pragma unroll
            for (int ni = 0; ni < 4; ni++) {
                int tcol = wn + ni*16 + ccol;
                float bcol = bias[lcb + tcol];
#pragma unroll
                for (int r = 0; r < 4; r++) {
                    int gr = wm + mi*16 + crow + r;
                    float v = (acc[mi][ni][r] + bcol) * scale;
                    if (QKVG) {
                        if (doRope) {
                            float vp = __shfl_xor(v, 1);   // partner col (tcol^1), same row
                            int s = (bm + gr) & (SEQ-1);
                            int jj = (tcol & 63) >> 1;
                            float ang = exp2f(-(float)jj * (13.287712379549449f/31.f));
                            float sn, cs;
                            sincosf((float)s * ang, &sn, &cs);
                            v = (tcol & 1) ? (v*cs + vp*sn) : (v*cs - vp*sn);
                        }
                        epib[(gr & (RPP-1))*128 + tcol] = bfbits(v);
                    } else {
                        epi[(gr & (RPP-1))*128 + tcol] = v;
                    }
                }
            }
        }
        __syncthreads();
        if (QKVG) {       // 16 thr/row x 16B, 16 rows/iter, 4 iters
            int rrow = tid >> 4, rc = (tid & 15) * 8;
#pragma unroll
            for (int it = 0; it < 4; it++) {
                int lr = it*16 + rrow;
                uint4 u = *(const uint4*)&epib[lr*128 + rc];
                *(uint4*)&obf[(size_t)(bm + pass*64 + lr)*No + lcb + rc] = u;
            }
        } else {          // 32 thr/row x 16B, 8 rows/iter, 4 iters
            int rrow = tid >> 5, rc = (tid & 31) * 4;
#pragma unroll
            for (int it = 0; it < 4; it++) {
                int lr = it*8 + rrow;
                uint4 u = *(const uint4*)&epi[lr*128 + rc];
                *(uint4*)&of32[(size_t)(bm + pass*32 + lr)*No + lcb + rc] = u;
            }
        }
        __syncthreads();
    }
}

// ---------------- retention per-chunk (bf16 in, inner_out in-place bf16, KV fp32) ----------------
__global__ __launch_bounds__(256) void ret_inner_kernel(
        const unsigned short* __restrict__ qry, const unsigned short* __restrict__ key,
        unsigned short* __restrict__ valio, float* __restrict__ kv_out,
        float* __restrict__ iscale_out) {
    int blk = blockIdx.x;           // (b*NH + h)*NC + c
    int c = blk & 63;
    int h = (blk >> 6) & 15;
    int b = blk >> 10;
    float dec = head_decay(h);

    __shared__ float uni[64*65];    // Q (stride 65) phase 1, V half (stride 64) phase 2
    __shared__ float Ks[CL][DK+1];
    __shared__ float Ss[CL][CL+1];
    __shared__ float ascale[CL];
    __shared__ float iscale[CL];

    int tid = threadIdx.x;
    size_t qkbase = ((size_t)(b*SEQ + c*CL))*DM + (size_t)h*DK;
#pragma unroll
    for (int it = 0; it < 2; it++) {
        int s = tid + it*256;       // 0..511 uint4 slots (8 bf16 each)
        int i = s >> 3, c0 = (s & 7)*8;
        uint4 uq = *(const uint4*)&qry[qkbase + (size_t)i*DM + c0];
        uint4 uk = *(const uint4*)&key[qkbase + (size_t)i*DM + c0];
        unpack8(uq, &uni[i*65 + c0]);
        unpack8(uk, &Ks[i][c0]);
    }
    if (tid < CL) {                 // attn_scale via explicit series (closed form cancels at h=15)
        float ssum = 0.f;
        for (int t = 0; t <= tid; t++) ssum += expf(dec * (float)t);
        ascale[tid] = sqrtf(ssum);
    }
    __syncthreads();

    // S = (Q @ K^T) * mask / ascale
    {
        int tx = tid & 15, ty = tid >> 4;
        float acc[4][4] = {};
        for (int d = 0; d < DK; d++) {
            float av[4], bv[4];
#pragma unroll
            for (int i = 0; i < 4; i++) av[i] = uni[(ty*4+i)*65 + d];
#pragma unroll
            for (int j = 0; j < 4; j++) bv[j] = Ks[tx*4+j][d];
#pragma unroll
            for (int i = 0; i < 4; i++)
#pragma unroll
                for (int j = 0; j < 4; j++)
                    acc[i][j] += av[i]*bv[j];
        }
#pragma unroll
        for (int i = 0; i < 4; i++) {
            int ri = ty*4 + i;
            float ra = 1.f / ascale[ri];
#pragma unroll
            for (int j = 0; j < 4; j++) {
                int cj = tx*4 + j;
                float m = (cj <= ri) ? expf(dec*(float)(ri-cj)) * ra : 0.f;
                Ss[ri][cj] = acc[i][j] * m;
            }
        }
    }
    __syncthreads();
    if (tid < CL) {                 // inner_scale = max(|row sum|, 1)
        float rs = 0.f;
        for (int j = 0; j < CL; j++) rs += Ss[tid][j];
        float isc = fmaxf(fabsf(rs), 1.f);
        iscale[tid] = isc;
        iscale_out[(size_t)blk*CL + tid] = isc;
    }

    // phase 2: (S/iscale)@V and K^T@V, V in two 64-col halves overlaying dead Q
    int txv = tid & 15, tyv = tid >> 4;
    int v0 = txv*4, i0 = tyv*4;
    size_t vbase = ((size_t)(b*SEQ + c*CL))*DG + (size_t)h*DV;
    for (int half = 0; half < 2; half++) {
        __syncthreads();            // prior uni readers done; iscale visible
#pragma unroll
        for (int it = 0; it < 2; it++) {
            int s = tid + it*256;
            int i = s >> 3, c0 = (s & 7)*8;
            uint4 uv = *(const uint4*)&valio[vbase + (size_t)i*DG + half*64 + c0];
            unpack8(uv, &uni[i*64 + c0]);
        }
        __syncthreads();
        float acc2[4][4] = {};
        float acc3[4][4] = {};
        for (int j = 0; j < CL; j++) {
            float4 vv = *(const float4*)&uni[j*64 + v0];
            float va[4] = {vv.x, vv.y, vv.z, vv.w};
#pragma unroll
            for (int r = 0; r < 4; r++) {
                float s  = Ss[i0+r][j];
                float kk = Ks[j][i0+r];
#pragma unroll
                for (int q = 0; q < 4; q++) {
                    acc2[r][q] += s*va[q];
                    acc3[r][q] += kk*va[q];
                }
            }
        }
#pragma unroll
        for (int r = 0; r < 4; r++) {
            int i = i0 + r;
            float inv = 1.f / iscale[i];
            uint2 p;
            p.x = pack2(acc2[r][0]*inv, acc2[r][1]*inv);
            p.y = pack2(acc2[r][2]*inv, acc2[r][3]*inv);
            *(uint2*)&valio[vbase + (size_t)i*DG + half*64 + v0] = p;   // own elems only
            float4 kvo = make_float4(acc3[r][0], acc3[r][1], acc3[r][2], acc3[r][3]);
            *(float4*)&kv_out[(size_t)blk*(DK*DV) + (size_t)i*DV + half*64 + v0] = kvo;
        }
    }
}

// ---------------- sequential scan over chunks (in-place KV -> cross_chunk) ----------------
__global__ __launch_bounds__(256) void ret_scan_kernel(float* __restrict__ kv,
        float* __restrict__ cscale_out) {
    int tid = threadIdx.x;
    int col = blockIdx.x*16 + ((tid >> 6) << 2) + (tid & 3);  // 0..4095
    int kp  = (tid >> 2) & 15;
    int v   = col & 127;
    int bh  = col >> 7;
    int h   = bh & 15;
    float dec = head_decay(h);
    float cdecay = expf(dec * (float)CL);
    float state[4] = {0.f, 0.f, 0.f, 0.f};
    float scale = 1.f;
    size_t base0 = (size_t)bh*NC*(DK*DV) + (size_t)(kp*4)*DV + v;
    float cur[4];
#pragma unroll
    for (int kk = 0; kk < 4; kk++) cur[kk] = kv[base0 + (size_t)kk*DV];
    for (int c = 0; c < NC; c++) {
        size_t base = base0 + (size_t)c*(DK*DV);
        float nxt[4];
        if (c+1 < NC) {
            size_t nb = base + (size_t)(DK*DV);
#pragma unroll
            for (int kk = 0; kk < 4; kk++) nxt[kk] = kv[nb + (size_t)kk*DV];
        }
        float inv = 1.f / scale;
#pragma unroll
        for (int kk = 0; kk < 4; kk++) kv[base + (size_t)kk*DV] = cur[kk]*inv;
        if (kp == 0) cscale_out[((size_t)bh*NC + c)*DV + v] = scale;
        float ssum = 0.f;
#pragma unroll
        for (int kk = 0; kk < 4; kk++) {
            state[kk] = state[kk]*cdecay + cur[kk];
            ssum += fabsf(state[kk]);
        }
        ssum += __shfl_xor(ssum, 4);
        ssum += __shfl_xor(ssum, 8);
        ssum += __shfl_xor(ssum, 16);
        ssum += __shfl_xor(ssum, 32);
        scale = fmaxf(ssum, 1.f);
        if (c+1 < NC) {
#pragma unroll
            for (int kk = 0; kk < 4; kk++) cur[kk] = nxt[kk];
        }
    }
}

// ---------------- cross_out + combine + groupnorm + silu(gate), in-place bf16 ----------------
__global__ __launch_bounds__(256) void ret_cross_kernel(
        const unsigned short* __restrict__ qry, const float* __restrict__ cross_chunk,
        unsigned short* __restrict__ valio, const float* __restrict__ iscale,
        const float* __restrict__ cscale, const unsigned short* __restrict__ gatebf,
        const float* __restrict__ gn_g, const float* __restrict__ gn_b) {
    int blk = blockIdx.x;
    int c = blk & 63, h = (blk >> 6) & 15, b = blk >> 10;
    float dec = head_decay(h);
    __shared__ float Qs[CL][DK+1];
    __shared__ float CC[DK][DV];
    __shared__ float asc[CL];
    __shared__ float idec[CL];

    int tid = threadIdx.x;
    size_t qbase = ((size_t)(b*SEQ + c*CL))*DM + (size_t)h*DK;
#pragma unroll
    for (int it = 0; it < 2; it++) {
        int s = tid + it*256;
        int i = s >> 3, c0 = (s & 7)*8;
        uint4 uq = *(const uint4*)&qry[qbase + (size_t)i*DM + c0];
        unpack8(uq, &Qs[i][c0]);
    }
    size_t cbase = (size_t)blk * (DK*DV);
#pragma unroll
    for (int t = 0; t < 32; t++) {
        int idx = tid + t*256;
        CC[idx >> 7][idx & 127] = cross_chunk[cbase + idx];
    }
    if (tid < CL) {
        float ssum = 0.f;
        for (int t = 0; t <= tid; t++) ssum += expf(dec * (float)t);
        asc[tid] = sqrtf(ssum);
    }
    __syncthreads();
    if (tid < CL) idec[tid] = expf(dec*(float)(tid+1)) * asc[CL-1] / asc[tid];
    __syncthreads();

    int txv = tid & 31, tyv = tid >> 5;
    int v0 = txv*4, i0 = tyv*8;
    float acc[8][4] = {};
    for (int k = 0; k < DK; k++) {
        float4 cv = *(const float4*)&CC[k][v0];
        float ca[4] = {cv.x, cv.y, cv.z, cv.w};
#pragma unroll
        for (int r = 0; r < 8; r++) {
            float qv = Qs[i0+r][k];
#pragma unroll
            for (int q = 0; q < 4; q++) acc[r][q] += qv*ca[q];
        }
    }
    float4 csv = *(const float4*)&cscale[(size_t)blk*DV + v0];
    float csa[4] = {csv.x, csv.y, csv.z, csv.w};
    float o[8][4];
    float s1[8], s2[8];
#pragma unroll
    for (int r = 0; r < 8; r++) {
        int i = i0 + r;
        float f2 = idec[i] / iscale[(size_t)blk*CL + i];
        size_t orow = ((size_t)(b*SEQ + c*CL + i))*DG + (size_t)h*DV + v0;
        uint2 iu = *(const uint2*)&valio[orow];
        float ioa[4] = { bf2f((unsigned short)(iu.x & 0xffff)),
                         bf2f((unsigned short)(iu.x >> 16)),
                         bf2f((unsigned short)(iu.y & 0xffff)),
                         bf2f((unsigned short)(iu.y >> 16)) };
        float rs1 = 0.f, rs2 = 0.f;
#pragma unroll
        for (int q = 0; q < 4; q++) {
            float ov = ioa[q]/csa[q] + acc[r][q]*f2;
            o[r][q] = ov;
            rs1 += ov; rs2 += ov*ov;
        }
        s1[r] = rs1; s2[r] = rs2;
    }
    // groupnorm over the head's 128 v's: reduce across 32 txv lanes
#pragma unroll
    for (int r = 0; r < 8; r++) {
#pragma unroll
        for (int m = 1; m <= 16; m <<= 1) {
            s1[r] += __shfl_xor(s1[r], m);
            s2[r] += __shfl_xor(s2[r], m);
        }
    }
#pragma unroll
    for (int r = 0; r < 8; r++) {
        int i = i0 + r;
        float mu = s1[r] * (1.f/DV);
        float var = s2[r] * (1.f/DV) - mu*mu;
        float rstd = rsqrtf(var + 1e-5f);
        size_t orow = ((size_t)(b*SEQ + c*CL + i))*DG + (size_t)h*DV + v0;
        uint2 gu = *(const uint2*)&gatebf[orow];
        float ga[4] = { bf2f((unsigned short)(gu.x & 0xffff)),
                        bf2f((unsigned short)(gu.x >> 16)),
                        bf2f((unsigned short)(gu.y & 0xffff)),
                        bf2f((unsigned short)(gu.y >> 16)) };
        float res[4];
#pragma unroll
        for (int q = 0; q < 4; q++) {
            int col = h*DV + v0 + q;
            float xn = (o[r][q] - mu)*rstd*gn_g[col] + gn_b[col];
            float sg = ga[q] / (1.f + expf(-ga[q]));
            res[q] = xn * sg;
        }
        uint2 p; p.x = pack2(res[0], res[1]); p.y = pack2(res[2], res[3]);
        *(uint2*)&valio[orow] = p;       // in-place: same elems this thread read
    }
}

extern "C" void kernel_launch(void* const* d_in, const int* in_sizes, int n_in,
                              void* d_out, int out_size, void* d_ws, size_t ws_size,
                              hipStream_t stream) {
    (void)in_sizes; (void)n_in; (void)out_size; (void)ws_size;
    const float* x    = (const float*)d_in[0];
    const float* W_q  = (const float*)d_in[2];
    const float* b_q  = (const float*)d_in[3];
    const float* W_k  = (const float*)d_in[4];
    const float* b_k  = (const float*)d_in[5];
    const float* W_v  = (const float*)d_in[6];
    const float* b_v  = (const float*)d_in[7];
    const float* W_g  = (const float*)d_in[8];
    const float* b_g  = (const float*)d_in[9];
    const float* W_o  = (const float*)d_in[10];
    const float* b_o  = (const float*)d_in[11];
    const float* ln_g = (const float*)d_in[12];
    const float* ln_b = (const float*)d_in[13];
    const float* gn_g = (const float*)d_in[14];
    const float* gn_b = (const float*)d_in[15];
    float* out = (float*)d_out;
    float* ws  = (float*)d_ws;

    // workspace layout (floats) — total ~39.2M floats = 157 MB
    float* keyb   = ws;                       //  4,194,304 (bf16 key 8192x1024)
    float* valb   = keyb   + 4194304;         //  8,388,608 (bf16 val->inner_out->acts 8192x2048)
    float* gateb  = valb   + 8388608;         //  8,388,608 (bf16 gate)
    float* kvbuf  = gateb  + 8388608;         // 16,777,216 fp32 KV->cross_chunk
    float* iscale = kvbuf  + 16777216;        //    131,072
    float* cscale = iscale + 131072;          //    262,144
    float* wobuf  = cscale + 262144;          //  1,048,576 (bf16 W_o 1024x2048)

    // bf16 views aliased over kvbuf (dead until ret_inner writes kvbuf)
    unsigned short* xbf  = (unsigned short*)kvbuf;             // 8,388,608 bf16
    unsigned short* Wcat = (unsigned short*)(kvbuf + 4194304); // 6,291,456 bf16 (6144x1024)
    unsigned short* Wo_bf  = (unsigned short*)wobuf;
    unsigned short* key_bf = (unsigned short*)keyb;
    unsigned short* val_bf = (unsigned short*)valb;
    unsigned short* gate_bf= (unsigned short*)gateb;
    unsigned short* qry_bf = (unsigned short*)out;   // d_out doubles as bf16 qry scratch

    ln_cvt_kernel<<<ROWS, 256, 0, stream>>>(x, ln_g, ln_b, xbf);
    cvt_bf16_kernel<<<(DM*DM/4 + 255)/256, 256, 0, stream>>>(W_q, Wcat,             DM*DM/4);
    cvt_bf16_kernel<<<(DM*DM/4 + 255)/256, 256, 0, stream>>>(W_k, Wcat + 1048576,   DM*DM/4);
    cvt_bf16_kernel<<<(DG*DM/4 + 255)/256, 256, 0, stream>>>(W_v, Wcat + 2097152,   DG*DM/4);
    cvt_bf16_kernel<<<(DG*DM/4 + 255)/256, 256, 0, stream>>>(W_g, Wcat + 4194304,   DG*DM/4);
    cvt_bf16_kernel<<<(DM*DG/4 + 255)/256, 256, 0, stream>>>(W_o, Wo_bf,            DM*DG/4);

    // fused QKVG: M=8192, Ntot=6144, K=1024 -> 3072 blocks
    gemm_mfma<true><<<(ROWS/128)*(6144/128), 256, 0, stream>>>(
        xbf, Wcat, DM, 6144, b_q, b_k, b_v, b_g,
        qry_bf, key_bf, val_bf, gate_bf);

    ret_inner_kernel<<<BATCH*NH*NC, 256, 0, stream>>>(qry_bf, key_bf, val_bf, kvbuf, iscale);
    ret_scan_kernel<<<256, 256, 0, stream>>>(kvbuf, cscale);
    ret_cross_kernel<<<BATCH*NH*NC, 256, 0, stream>>>(qry_bf, kvbuf, val_bf, iscale, cscale,
                                                      gate_bf, gn_g, gn_b);

    // Wo: M=8192, N=1024, K=2048 -> 512 blocks, fp32 out
    gemm_mfma<false><<<(ROWS/128)*(DM/128), 256, 0, stream>>>(
        val_bf, Wo_bf, DG, DM, b_o, nullptr, nullptr, nullptr,
        out, nullptr, nullptr, nullptr);
}

// Round 6
// 656.615 us; speedup vs baseline: 3.4921x; 1.0640x over previous
//
#include <hip/hip_runtime.h>
#include <hip/hip_bf16.h>
#include <math.h>

#define BATCH 2
#define SEQ 4096
#define DM 1024
#define NH 16
#define DK 64
#define DV 128
#define NC 64     // number of chunks
#define CL 64     // chunk length
#define ROWS (BATCH*SEQ)   // 8192
#define DG (DM*2)          // 2048 (val/gate width)

typedef __attribute__((ext_vector_type(8))) short short8;
typedef __attribute__((ext_vector_type(4))) float floatx4;

__device__ __forceinline__ float head_decay(int h) {
    return logf(1.0f - exp2f(-5.0f - (float)h));
}
__device__ __forceinline__ unsigned short bfbits(float v) {
    __hip_bfloat16 h = __float2bfloat16(v);
    return *(unsigned short*)&h;
}
__device__ __forceinline__ float bf2f(unsigned short u) {
    unsigned x = ((unsigned)u) << 16;
    return *(float*)&x;
}
__device__ __forceinline__ unsigned pack2(float a, float b) {
    return (unsigned)bfbits(a) | ((unsigned)bfbits(b) << 16);
}
__device__ __forceinline__ void unpack8(uint4 u, float* dst) {
    dst[0]=bf2f((unsigned short)(u.x&0xffff)); dst[1]=bf2f((unsigned short)(u.x>>16));
    dst[2]=bf2f((unsigned short)(u.y&0xffff)); dst[3]=bf2f((unsigned short)(u.y>>16));
    dst[4]=bf2f((unsigned short)(u.z&0xffff)); dst[5]=bf2f((unsigned short)(u.z>>16));
    dst[6]=bf2f((unsigned short)(u.w&0xffff)); dst[7]=bf2f((unsigned short)(u.w>>16));
}
__device__ __forceinline__ void gld_lds16(const unsigned short* g, unsigned short* l) {
    __builtin_amdgcn_global_load_lds(
        (const __attribute__((address_space(1))) unsigned int*)g,
        (__attribute__((address_space(3))) unsigned int*)l, 16, 0, 0);
}

// ---------------- LN + cast to bf16: one block per row ----------------
__global__ __launch_bounds__(256) void ln_cvt_kernel(const float* __restrict__ x,
        const float* __restrict__ g, const float* __restrict__ b,
        unsigned short* __restrict__ xbf) {
    int row = blockIdx.x;
    const float* xr = x + (size_t)row * DM;
    int c0 = threadIdx.x * 4;
    float4 v = *(const float4*)&xr[c0];
    float s1 = v.x + v.y + v.z + v.w;
    float s2 = v.x*v.x + v.y*v.y + v.z*v.z + v.w*v.w;
#pragma unroll
    for (int off = 32; off > 0; off >>= 1) {
        s1 += __shfl_down(s1, off);
        s2 += __shfl_down(s2, off);
    }
    __shared__ float a1[4], a2[4];
    int wid = threadIdx.x >> 6;
    if ((threadIdx.x & 63) == 0) { a1[wid] = s1; a2[wid] = s2; }
    __syncthreads();
    s1 = a1[0] + a1[1] + a1[2] + a1[3];
    s2 = a2[0] + a2[1] + a2[2] + a2[3];
    float mu = s1 * (1.f/DM);
    float var = s2 * (1.f/DM) - mu*mu;
    float rstd = rsqrtf(var + 1e-5f);
    float o0 = (v.x - mu)*rstd*g[c0+0] + b[c0+0];
    float o1 = (v.y - mu)*rstd*g[c0+1] + b[c0+1];
    float o2 = (v.z - mu)*rstd*g[c0+2] + b[c0+2];
    float o3 = (v.w - mu)*rstd*g[c0+3] + b[c0+3];
    uint2 p; p.x = pack2(o0, o1); p.y = pack2(o2, o3);
    *(uint2*)&xbf[(size_t)row*DM + c0] = p;
}

// ---------------- fp32 -> bf16 weight conversion ----------------
__global__ __launch_bounds__(256) void cvt_bf16_kernel(const float* __restrict__ src,
        unsigned short* __restrict__ dst, int n4) {
    int i = blockIdx.x * 256 + threadIdx.x;
    if (i < n4) {
        float4 v = ((const float4*)src)[i];
        uint2 p; p.x = pack2(v.x, v.y); p.y = pack2(v.z, v.w);
        ((uint2*)dst)[i] = p;
    }
}

// ---------------- bf16 MFMA NT GEMM, 128x128 tile, BK=64, XOR-swizzled LDS ----------------
// Staging: thread tid stages row r=tid>>3, col-block q=tid&7 -> global col-block
// q^(r&7). Element (r,k) sits at LDS r*64 + ((k>>3)^(r&7))*8 shorts, so the
// fragment ds_read_b128 (16 lanes, same k-block, rows fm=0..15) spreads over
// 8 bank-pairs -> 2-way = free (was 8-way at BK=32). 32 MFMA per barrier
// (AITER ratio), halving barrier drains vs BK=32. Epilogue tile aliases
// As/Bs (dead after final in-loop barrier) -> LDS stays 32 KB.
// QKVG=true: A(8192x1024) x Wcat(6144x1024)^T; per-segment epilogue
//   seg0 Q(rope) seg1 K(rope, x.125) seg2,3 V seg4,5 G (all bf16 out).
// QKVG=false: A x W^T + b0 -> o0 (fp32). XCD-aware 1D raster.
template<bool QKVG>
__global__ __launch_bounds__(256) void gemm_mfma(
        const unsigned short* __restrict__ A, const unsigned short* __restrict__ W,
        int K, int Ntot,
        const float* __restrict__ b0, const float* __restrict__ b1,
        const float* __restrict__ b2, const float* __restrict__ b3,
        void* __restrict__ o0, void* __restrict__ o1,
        void* __restrict__ o2, void* __restrict__ o3) {
    const int nbn = Ntot >> 7;
    const int nb  = (ROWS >> 7) * nbn;
    const int per = nb >> 3;
    int id = blockIdx.x;
    int logical = (id & 7) * per + (id >> 3);
    const int in_grp = 8 * nbn;
    int g   = logical / in_grp;
    int rem = logical - g * in_grp;
    const int bm = (g * 8 + (rem & 7)) << 7;
    const int bn = (rem >> 3) << 7;

    __shared__ unsigned short smem[16384];     // 32 KB: As[128][64] | Bs[128][64]; epi aliases
    unsigned short* As = smem;
    unsigned short* Bs = smem + 8192;

    const int tid = threadIdx.x;
    const int wave = tid >> 6, lane = tid & 63;
    const int wm = (wave & 1) * 64, wn = (wave >> 1) * 64;

    // staging map: row sr=tid>>3 (32-row rounds), col-block swizzled by row
    const int sr = tid >> 3;
    const int scol = (((tid & 7) ^ (sr & 7)) * 8);
    const unsigned short* Ag = A + (size_t)(bm + sr) * K + scol;
    const unsigned short* Wg = W + (size_t)(bn + sr) * K + scol;
    const int fm = lane & 15;
    const int kq = lane >> 4;                  // k-block quarter 0..3

    floatx4 acc[4][4] = {};
    for (int k0 = 0; k0 < K; k0 += 64) {
#pragma unroll
        for (int t = 0; t < 4; t++) {
            gld_lds16(Ag + (size_t)(t*32)*K + k0, &As[t*2048 + tid*8]);
            gld_lds16(Wg + (size_t)(t*32)*K + k0, &Bs[t*2048 + tid*8]);
        }
        __syncthreads();
#pragma unroll
        for (int half = 0; half < 2; half++) {
            const int kb = half*4 + kq;        // k-block 0..7
            short8 af[4], bfv[4];
#pragma unroll
            for (int mi = 0; mi < 4; mi++) {
                int r = wm + mi*16 + fm;
                af[mi] = *(const short8*)&As[r*64 + ((kb ^ (r & 7))*8)];
            }
#pragma unroll
            for (int ni = 0; ni < 4; ni++) {
                int r = wn + ni*16 + fm;
                bfv[ni] = *(const short8*)&Bs[r*64 + ((kb ^ (r & 7))*8)];
            }
#pragma unroll
            for (int mi = 0; mi < 4; mi++)
#pragma unroll
                for (int ni = 0; ni < 4; ni++)
                    acc[mi][ni] = __builtin_amdgcn_mfma_f32_16x16x32_bf16(
                                      af[mi], bfv[ni], acc[mi][ni], 0, 0, 0);
        }
        __syncthreads();
    }

    // segment routing (block-uniform)
    float scale = 1.f; bool doRope = false;
    const float* bias; int No, lcb;
    unsigned short* obf = nullptr; float* of32 = nullptr;
    if (QKVG) {
        int seg = bn >> 10;
        if (seg == 0)      { obf = (unsigned short*)o0; bias = b0; No = 1024; lcb = bn;        doRope = true; }
        else if (seg == 1) { obf = (unsigned short*)o1; bias = b1; No = 1024; lcb = bn - 1024; doRope = true; scale = 0.125f; }
        else if (seg <= 3) { obf = (unsigned short*)o2; bias = b2; No = 2048; lcb = bn - 2048; }
        else               { obf = (unsigned short*)o3; bias = b3; No = 2048; lcb = bn - 4096; }
    } else {
        of32 = (float*)o0; bias = b0; No = Ntot; lcb = bn;
    }

    // epilogue through LDS (aliases As/Bs, safe after final in-loop barrier):
    // 2 passes of 64 rows; bf16 uses 16 KB as [64][128] shorts, fp32 32 KB as [64][128] floats
    const int crow = (lane >> 4) * 4, ccol = lane & 15;
    unsigned short* epib = smem;
    float* epif = (float*)smem;
    for (int pass = 0; pass < 2; pass++) {
#pragma unroll
        for (int mi = 0; mi < 4; mi++) {
            if (((wm + mi*16) >> 6) != pass) continue;   // wave-uniform
#pragma unroll
            for (int ni = 0; ni < 4; ni++) {
                int tcol = wn + ni*16 + ccol;
                float bcol = bias[lcb + tcol];
#pragma unroll
                for (int r = 0; r < 4; r++) {
                    int gr = wm + mi*16 + crow + r;
                    float v = (acc[mi][ni][r] + bcol) * scale;
                    if (QKVG) {
                        if (doRope) {
                            float vp = __shfl_xor(v, 1);   // partner col (tcol^1), same row
                            int s = (bm + gr) & (SEQ-1);
                            int jj = (tcol & 63) >> 1;
                            float ang = exp2f(-(float)jj * (13.287712379549449f/31.f));
                            float sn, cs;
                            sincosf((float)s * ang, &sn, &cs);
                            v = (tcol & 1) ? (v*cs + vp*sn) : (v*cs - vp*sn);
                        }
                        epib[(gr & 63)*128 + tcol] = bfbits(v);
                    } else {
                        epif[(gr & 63)*128 + tcol] = v;
                    }
                }
            }
        }
        __syncthreads();
        if (QKVG) {       // 16 thr/row x 16B => 256B rows; 16 rows/iter, 4 iters
            int rrow = tid >> 4, rc = (tid & 15) * 8;
#pragma unroll
            for (int it = 0; it < 4; it++) {
                int lr = it*16 + rrow;
                uint4 u = *(const uint4*)&epib[lr*128 + rc];
                *(uint4*)&obf[(size_t)(bm + pass*64 + lr)*No + lcb + rc] = u;
            }
        } else {          // 32 thr/row x 16B => 512B rows; 8 rows/iter, 8 iters
            int rrow = tid >> 5, rc = (tid & 31) * 4;
#pragma unroll
            for (int it = 0; it < 8; it++) {
                int lr = it*8 + rrow;
                uint4 u = *(const uint4*)&epif[lr*128 + rc];
                *(uint4*)&of32[(size_t)(bm + pass*64 + lr)*No + lcb + rc] = u;
            }
        }
        __syncthreads();
    }
}

// ---------------- retention per-chunk (bf16 in, inner_out in-place bf16, KV fp32) ----------------
__global__ __launch_bounds__(256) void ret_inner_kernel(
        const unsigned short* __restrict__ qry, const unsigned short* __restrict__ key,
        unsigned short* __restrict__ valio, float* __restrict__ kv_out,
        float* __restrict__ iscale_out) {
    int blk = blockIdx.x;           // (b*NH + h)*NC + c
    int c = blk & 63;
    int h = (blk >> 6) & 15;
    int b = blk >> 10;
    float dec = head_decay(h);

    __shared__ float uni[64*65];    // Q (stride 65) phase 1, V half (stride 64) phase 2
    __shared__ float Ks[CL][DK+1];
    __shared__ float Ss[CL][CL+1];
    __shared__ float ascale[CL];
    __shared__ float iscale[CL];

    int tid = threadIdx.x;
    size_t qkbase = ((size_t)(b*SEQ + c*CL))*DM + (size_t)h*DK;
#pragma unroll
    for (int it = 0; it < 2; it++) {
        int s = tid + it*256;       // 0..511 uint4 slots (8 bf16 each)
        int i = s >> 3, c0 = (s & 7)*8;
        uint4 uq = *(const uint4*)&qry[qkbase + (size_t)i*DM + c0];
        uint4 uk = *(const uint4*)&key[qkbase + (size_t)i*DM + c0];
        unpack8(uq, &uni[i*65 + c0]);
        unpack8(uk, &Ks[i][c0]);
    }
    if (tid < CL) {                 // attn_scale via explicit series (closed form cancels at h=15)
        float ssum = 0.f;
        for (int t = 0; t <= tid; t++) ssum += expf(dec * (float)t);
        ascale[tid] = sqrtf(ssum);
    }
    __syncthreads();

    // S = (Q @ K^T) * mask / ascale
    {
        int tx = tid & 15, ty = tid >> 4;
        float acc[4][4] = {};
        for (int d = 0; d < DK; d++) {
            float av[4], bv[4];
#pragma unroll
            for (int i = 0; i < 4; i++) av[i] = uni[(ty*4+i)*65 + d];
#pragma unroll
            for (int j = 0; j < 4; j++) bv[j] = Ks[tx*4+j][d];
#pragma unroll
            for (int i = 0; i < 4; i++)
#pragma unroll
                for (int j = 0; j < 4; j++)
                    acc[i][j] += av[i]*bv[j];
        }
#pragma unroll
        for (int i = 0; i < 4; i++) {
            int ri = ty*4 + i;
            float ra = 1.f / ascale[ri];
#pragma unroll
            for (int j = 0; j < 4; j++) {
                int cj = tx*4 + j;
                float m = (cj <= ri) ? expf(dec*(float)(ri-cj)) * ra : 0.f;
                Ss[ri][cj] = acc[i][j] * m;
            }
        }
    }
    __syncthreads();
    if (tid < CL) {                 // inner_scale = max(|row sum|, 1)
        float rs = 0.f;
        for (int j = 0; j < CL; j++) rs += Ss[tid][j];
        float isc = fmaxf(fabsf(rs), 1.f);
        iscale[tid] = isc;
        iscale_out[(size_t)blk*CL + tid] = isc;
    }

    // phase 2: (S/iscale)@V and K^T@V, V in two 64-col halves overlaying dead Q
    int txv = tid & 15, tyv = tid >> 4;
    int v0 = txv*4, i0 = tyv*4;
    size_t vbase = ((size_t)(b*SEQ + c*CL))*DG + (size_t)h*DV;
    for (int half = 0; half < 2; half++) {
        __syncthreads();            // prior uni readers done; iscale visible
#pragma unroll
        for (int it = 0; it < 2; it++) {
            int s = tid + it*256;
            int i = s >> 3, c0 = (s & 7)*8;
            uint4 uv = *(const uint4*)&valio[vbase + (size_t)i*DG + half*64 + c0];
            unpack8(uv, &uni[i*64 + c0]);
        }
        __syncthreads();
        float acc2[4][4] = {};
        float acc3[4][4] = {};
        for (int j = 0; j < CL; j++) {
            float4 vv = *(const float4*)&uni[j*64 + v0];
            float va[4] = {vv.x, vv.y, vv.z, vv.w};
#pragma unroll
            for (int r = 0; r < 4; r++) {
                float s  = Ss[i0+r][j];
                float kk = Ks[j][i0+r];
#pragma unroll
                for (int q = 0; q < 4; q++) {
                    acc2[r][q] += s*va[q];
                    acc3[r][q] += kk*va[q];
                }
            }
        }
#pragma unroll
        for (int r = 0; r < 4; r++) {
            int i = i0 + r;
            float inv = 1.f / iscale[i];
            uint2 p;
            p.x = pack2(acc2[r][0]*inv, acc2[r][1]*inv);
            p.y = pack2(acc2[r][2]*inv, acc2[r][3]*inv);
            *(uint2*)&valio[vbase + (size_t)i*DG + half*64 + v0] = p;   // own elems only
            float4 kvo = make_float4(acc3[r][0], acc3[r][1], acc3[r][2], acc3[r][3]);
            *(float4*)&kv_out[(size_t)blk*(DK*DV) + (size_t)i*DV + half*64 + v0] = kvo;
        }
    }
}

// ---------------- sequential scan over chunks (in-place KV -> cross_chunk) ----------------
__global__ __launch_bounds__(256) void ret_scan_kernel(float* __restrict__ kv,
        float* __restrict__ cscale_out) {
    int tid = threadIdx.x;
    int col = blockIdx.x*16 + ((tid >> 6) << 2) + (tid & 3);  // 0..4095
    int kp  = (tid >> 2) & 15;
    int v   = col & 127;
    int bh  = col >> 7;
    int h   = bh & 15;
    float dec = head_decay(h);
    float cdecay = expf(dec * (float)CL);
    float state[4] = {0.f, 0.f, 0.f, 0.f};
    float scale = 1.f;
    size_t base0 = (size_t)bh*NC*(DK*DV) + (size_t)(kp*4)*DV + v;
    float cur[4];
#pragma unroll
    for (int kk = 0; kk < 4; kk++) cur[kk] = kv[base0 + (size_t)kk*DV];
    for (int c = 0; c < NC; c++) {
        size_t base = base0 + (size_t)c*(DK*DV);
        float nxt[4];
        if (c+1 < NC) {
            size_t nb = base + (size_t)(DK*DV);
#pragma unroll
            for (int kk = 0; kk < 4; kk++) nxt[kk] = kv[nb + (size_t)kk*DV];
        }
        float inv = 1.f / scale;
#pragma unroll
        for (int kk = 0; kk < 4; kk++) kv[base + (size_t)kk*DV] = cur[kk]*inv;
        if (kp == 0) cscale_out[((size_t)bh*NC + c)*DV + v] = scale;
        float ssum = 0.f;
#pragma unroll
        for (int kk = 0; kk < 4; kk++) {
            state[kk] = state[kk]*cdecay + cur[kk];
            ssum += fabsf(state[kk]);
        }
        ssum += __shfl_xor(ssum, 4);
        ssum += __shfl_xor(ssum, 8);
        ssum += __shfl_xor(ssum, 16);
        ssum += __shfl_xor(ssum, 32);
        scale = fmaxf(ssum, 1.f);
        if (c+1 < NC) {
#pragma unroll
            for (int kk = 0; kk < 4; kk++) cur[kk] = nxt[kk];
        }
    }
}

// ---------------- cross_out + combine + groupnorm + silu(gate), in-place bf16 ----------------
__global__ __launch_bounds__(256) void ret_cross_kernel(
        const unsigned short* __restrict__ qry, const float* __restrict__ cross_chunk,
        unsigned short* __restrict__ valio, const float* __restrict__ iscale,
        const float* __restrict__ cscale, const unsigned short* __restrict__ gatebf,
        const float* __restrict__ gn_g, const float* __restrict__ gn_b) {
    int blk = blockIdx.x;
    int c = blk & 63, h = (blk >> 6) & 15, b = blk >> 10;
    float dec = head_decay(h);
    __shared__ float Qs[CL][DK+1];
    __shared__ float CC[DK][DV];
    __shared__ float asc[CL];
    __shared__ float idec[CL];

    int tid = threadIdx.x;
    size_t qbase = ((size_t)(b*SEQ + c*CL))*DM + (size_t)h*DK;
#pragma unroll
    for (int it = 0; it < 2; it++) {
        int s = tid + it*256;
        int i = s >> 3, c0 = (s & 7)*8;
        uint4 uq = *(const uint4*)&qry[qbase + (size_t)i*DM + c0];
        unpack8(uq, &Qs[i][c0]);
    }
    size_t cbase = (size_t)blk * (DK*DV);
#pragma unroll
    for (int t = 0; t < 32; t++) {
        int idx = tid + t*256;
        CC[idx >> 7][idx & 127] = cross_chunk[cbase + idx];
    }
    if (tid < CL) {
        float ssum = 0.f;
        for (int t = 0; t <= tid; t++) ssum += expf(dec * (float)t);
        asc[tid] = sqrtf(ssum);
    }
    __syncthreads();
    if (tid < CL) idec[tid] = expf(dec*(float)(tid+1)) * asc[CL-1] / asc[tid];
    __syncthreads();

    int txv = tid & 31, tyv = tid >> 5;
    int v0 = txv*4, i0 = tyv*8;
    float acc[8][4] = {};
    for (int k = 0; k < DK; k++) {
        float4 cv = *(const float4*)&CC[k][v0];
        float ca[4] = {cv.x, cv.y, cv.z, cv.w};
#pragma unroll
        for (int r = 0; r < 8; r++) {
            float qv = Qs[i0+r][k];
#pragma unroll
            for (int q = 0; q < 4; q++) acc[r][q] += qv*ca[q];
        }
    }
    float4 csv = *(const float4*)&cscale[(size_t)blk*DV + v0];
    float csa[4] = {csv.x, csv.y, csv.z, csv.w};
    float o[8][4];
    float s1[8], s2[8];
#pragma unroll
    for (int r = 0; r < 8; r++) {
        int i = i0 + r;
        float f2 = idec[i] / iscale[(size_t)blk*CL + i];
        size_t orow = ((size_t)(b*SEQ + c*CL + i))*DG + (size_t)h*DV + v0;
        uint2 iu = *(const uint2*)&valio[orow];
        float ioa[4] = { bf2f((unsigned short)(iu.x & 0xffff)),
                         bf2f((unsigned short)(iu.x >> 16)),
                         bf2f((unsigned short)(iu.y & 0xffff)),
                         bf2f((unsigned short)(iu.y >> 16)) };
        float rs1 = 0.f, rs2 = 0.f;
#pragma unroll
        for (int q = 0; q < 4; q++) {
            float ov = ioa[q]/csa[q] + acc[r][q]*f2;
            o[r][q] = ov;
            rs1 += ov; rs2 += ov*ov;
        }
        s1[r] = rs1; s2[r] = rs2;
    }
    // groupnorm over the head's 128 v's: reduce across 32 txv lanes
#pragma unroll
    for (int r = 0; r < 8; r++) {
#pragma unroll
        for (int m = 1; m <= 16; m <<= 1) {
            s1[r] += __shfl_xor(s1[r], m);
            s2[r] += __shfl_xor(s2[r], m);
        }
    }
#pragma unroll
    for (int r = 0; r < 8; r++) {
        int i = i0 + r;
        float mu = s1[r] * (1.f/DV);
        float var = s2[r] * (1.f/DV) - mu*mu;
        float rstd = rsqrtf(var + 1e-5f);
        size_t orow = ((size_t)(b*SEQ + c*CL + i))*DG + (size_t)h*DV + v0;
        uint2 gu = *(const uint2*)&gatebf[orow];
        float ga[4] = { bf2f((unsigned short)(gu.x & 0xffff)),
                        bf2f((unsigned short)(gu.x >> 16)),
                        bf2f((unsigned short)(gu.y & 0xffff)),
                        bf2f((unsigned short)(gu.y >> 16)) };
        float res[4];
#pragma unroll
        for (int q = 0; q < 4; q++) {
            int col = h*DV + v0 + q;
            float xn = (o[r][q] - mu)*rstd*gn_g[col] + gn_b[col];
            float sg = ga[q] / (1.f + expf(-ga[q]));
            res[q] = xn * sg;
        }
        uint2 p; p.x = pack2(res[0], res[1]); p.y = pack2(res[2], res[3]);
        *(uint2*)&valio[orow] = p;       // in-place: same elems this thread read
    }
}

extern "C" void kernel_launch(void* const* d_in, const int* in_sizes, int n_in,
                              void* d_out, int out_size, void* d_ws, size_t ws_size,
                              hipStream_t stream) {
    (void)in_sizes; (void)n_in; (void)out_size; (void)ws_size;
    const float* x    = (const float*)d_in[0];
    const float* W_q  = (const float*)d_in[2];
    const float* b_q  = (const float*)d_in[3];
    const float* W_k  = (const float*)d_in[4];
    const float* b_k  = (const float*)d_in[5];
    const float* W_v  = (const float*)d_in[6];
    const float* b_v  = (const float*)d_in[7];
    const float* W_g  = (const float*)d_in[8];
    const float* b_g  = (const float*)d_in[9];
    const float* W_o  = (const float*)d_in[10];
    const float* b_o  = (const float*)d_in[11];
    const float* ln_g = (const float*)d_in[12];
    const float* ln_b = (const float*)d_in[13];
    const float* gn_g = (const float*)d_in[14];
    const float* gn_b = (const float*)d_in[15];
    float* out = (float*)d_out;
    float* ws  = (float*)d_ws;

    // workspace layout (floats) — total ~39.2M floats = 157 MB
    float* keyb   = ws;                       //  4,194,304 (bf16 key 8192x1024)
    float* valb   = keyb   + 4194304;         //  8,388,608 (bf16 val->inner_out->acts 8192x2048)
    float* gateb  = valb   + 8388608;         //  8,388,608 (bf16 gate)
    float* kvbuf  = gateb  + 8388608;         // 16,777,216 fp32 KV->cross_chunk
    float* iscale = kvbuf  + 16777216;        //    131,072
    float* cscale = iscale + 131072;          //    262,144
    float* wobuf  = cscale + 262144;          //  1,048,576 (bf16 W_o 1024x2048)

    // bf16 views aliased over kvbuf (dead until ret_inner writes kvbuf)
    unsigned short* xbf  = (unsigned short*)kvbuf;             // 8,388,608 bf16
    unsigned short* Wcat = (unsigned short*)(kvbuf + 4194304); // 6,291,456 bf16 (6144x1024)
    unsigned short* Wo_bf  = (unsigned short*)wobuf;
    unsigned short* key_bf = (unsigned short*)keyb;
    unsigned short* val_bf = (unsigned short*)valb;
    unsigned short* gate_bf= (unsigned short*)gateb;
    unsigned short* qry_bf = (unsigned short*)out;   // d_out doubles as bf16 qry scratch

    ln_cvt_kernel<<<ROWS, 256, 0, stream>>>(x, ln_g, ln_b, xbf);
    cvt_bf16_kernel<<<(DM*DM/4 + 255)/256, 256, 0, stream>>>(W_q, Wcat,             DM*DM/4);
    cvt_bf16_kernel<<<(DM*DM/4 + 255)/256, 256, 0, stream>>>(W_k, Wcat + 1048576,   DM*DM/4);
    cvt_bf16_kernel<<<(DG*DM/4 + 255)/256, 256, 0, stream>>>(W_v, Wcat + 2097152,   DG*DM/4);
    cvt_bf16_kernel<<<(DG*DM/4 + 255)/256, 256, 0, stream>>>(W_g, Wcat + 4194304,   DG*DM/4);
    cvt_bf16_kernel<<<(DM*DG/4 + 255)/256, 256, 0, stream>>>(W_o, Wo_bf,            DM*DG/4);

    // fused QKVG: M=8192, Ntot=6144, K=1024 -> 3072 blocks
    gemm_mfma<true><<<(ROWS/128)*(6144/128), 256, 0, stream>>>(
        xbf, Wcat, DM, 6144, b_q, b_k, b_v, b_g,
        qry_bf, key_bf, val_bf, gate_bf);

    ret_inner_kernel<<<BATCH*NH*NC, 256, 0, stream>>>(qry_bf, key_bf, val_bf, kvbuf, iscale);
    ret_scan_kernel<<<256, 256, 0, stream>>>(kvbuf, cscale);
    ret_cross_kernel<<<BATCH*NH*NC, 256, 0, stream>>>(qry_bf, kvbuf, val_bf, iscale, cscale,
                                                      gate_bf, gn_g, gn_b);

    // Wo: M=8192, N=1024, K=2048 -> 512 blocks, fp32 out
    gemm_mfma<false><<<(ROWS/128)*(DM/128), 256, 0, stream>>>(
        val_bf, Wo_bf, DG, DM, b_o, nullptr, nullptr, nullptr,
        out, nullptr, nullptr, nullptr);
}